// Round 1
// baseline (1468.850 us; speedup 1.0000x reference)
//
#include <hip/hip_runtime.h>
#include <hip/hip_bf16.h>

#define NNODES 100000
#define NEDGES 1600000
#define HDIM 256
#define ADIM 64
#define NHEADS 3
#define FDIM 192   // NHEADS*ADIM
#define NGRAPH 64
#define NPART 64   // privatized partitions for graph-sum atomics

// ---------------- feat = emb[h0] @ W_fc  (fp32 tiled GEMM with A-gather) ----
// block 256 threads, tile 64 rows x 192 cols, K-chunks of 32
__global__ __launch_bounds__(256) void feat_gemm_kernel(
    const int* __restrict__ h0, const float* __restrict__ emb,
    const float* __restrict__ Wfc, float* __restrict__ feat, int N)
{
  __shared__ float As[64 * 32];
  __shared__ float Bs[32 * FDIM];
  const int tid = threadIdx.x;
  const int tx = tid & 31;   // col group: cols tx + 32*c
  const int ty = tid >> 5;   // 0..7   : rows ty + 8*j
  const int n0 = blockIdx.x * 64;

  float acc[8][6];
#pragma unroll
  for (int j = 0; j < 8; ++j)
#pragma unroll
    for (int c = 0; c < 6; ++c) acc[j][c] = 0.f;

  for (int k0 = 0; k0 < HDIM; k0 += 32) {
    // A tile: 64 rows x 32 k  (gather emb rows via h0)
#pragma unroll
    for (int q = 0; q < 2; ++q) {
      int idx = tid * 2 + q;          // 0..511 float4 slots
      int row = idx >> 3;
      int c4  = idx & 7;
      int n = n0 + row;
      float4 v = make_float4(0.f, 0.f, 0.f, 0.f);
      if (n < N) {
        int e = h0[n];
        v = *reinterpret_cast<const float4*>(&emb[(size_t)e * HDIM + k0 + c4 * 4]);
      }
      *reinterpret_cast<float4*>(&As[row * 32 + c4 * 4]) = v;
    }
    // B tile: 32 k x 192 cols
#pragma unroll
    for (int q = 0; q < 6; ++q) {
      int idx = tid + q * 256;        // 0..1535 float4 slots
      int kk = idx / 48;
      int c4 = idx % 48;
      float4 v = *reinterpret_cast<const float4*>(&Wfc[(size_t)(k0 + kk) * FDIM + c4 * 4]);
      *reinterpret_cast<float4*>(&Bs[kk * FDIM + c4 * 4]) = v;
    }
    __syncthreads();
#pragma unroll
    for (int kk = 0; kk < 32; ++kk) {
      float b[6];
#pragma unroll
      for (int c = 0; c < 6; ++c) b[c] = Bs[kk * FDIM + tx + 32 * c];
#pragma unroll
      for (int j = 0; j < 8; ++j) {
        float a = As[(ty + j * 8) * 32 + kk];
#pragma unroll
        for (int c = 0; c < 6; ++c) acc[j][c] += a * b[c];
      }
    }
    __syncthreads();
  }
#pragma unroll
  for (int j = 0; j < 8; ++j) {
    int n = n0 + ty + j * 8;
    if (n < N) {
#pragma unroll
      for (int c = 0; c < 6; ++c)
        feat[(size_t)n * FDIM + tx + 32 * c] = acc[j][c];
    }
  }
}

// ---------------- el/er: per-node attention dots -----------------
__global__ __launch_bounds__(256) void attn_kernel(
    const float* __restrict__ feat, const float* __restrict__ attn_l,
    const float* __restrict__ attn_r, float* __restrict__ el,
    float* __restrict__ er, int N)
{
  int wid  = blockIdx.x * (blockDim.x >> 6) + (threadIdx.x >> 6);
  int lane = threadIdx.x & 63;
  if (wid >= N) return;
  float sl[3], sr[3];
#pragma unroll
  for (int h = 0; h < 3; ++h) {
    float v = feat[(size_t)wid * FDIM + h * 64 + lane];
    sl[h] = v * attn_l[h * 64 + lane];
    sr[h] = v * attn_r[h * 64 + lane];
  }
#pragma unroll
  for (int s = 32; s > 0; s >>= 1) {
#pragma unroll
    for (int h = 0; h < 3; ++h) {
      sl[h] += __shfl_xor(sl[h], s, 64);
      sr[h] += __shfl_xor(sr[h], s, 64);
    }
  }
  if (lane == 0) {
#pragma unroll
    for (int h = 0; h < 3; ++h) { el[wid * 3 + h] = sl[h]; er[wid * 3 + h] = sr[h]; }
  }
}

// ---------------- edge pass: denom += w ; rstU[dst] += w * feat[src] --------
// one wave per edge; lane owns one of 64 'a' slots per head
__global__ __launch_bounds__(256) void edge_kernel(
    const int* __restrict__ src, const int* __restrict__ dst,
    const float* __restrict__ el, const float* __restrict__ er,
    const float* __restrict__ feat, float* __restrict__ denom,
    float* __restrict__ rstU, int E)
{
  int lane = threadIdx.x & 63;
  int wid  = blockIdx.x * (blockDim.x >> 6) + (threadIdx.x >> 6);
  int nw   = gridDim.x * (blockDim.x >> 6);
  for (int e = wid; e < E; e += nw) {
    int s = src[e], d = dst[e];
    float w[3];
#pragma unroll
    for (int h = 0; h < 3; ++h) {
      float ev = el[s * 3 + h] + er[d * 3 + h];
      ev = ev > 0.f ? ev : 0.2f * ev;   // leaky_relu 0.2
      w[h] = __expf(ev);                // no max-shift needed: |ev| << 1
    }
    if (lane < 3) atomicAdd(&denom[d * 3 + lane], w[lane]);
#pragma unroll
    for (int h = 0; h < 3; ++h) {
      float v = feat[(size_t)s * FDIM + h * 64 + lane];
      atomicAdd(&rstU[(size_t)d * FDIM + h * 64 + lane], w[h] * v);
    }
  }
}

// ---------------- per-node: normalize + bias + relu + head-mean + MLP -------
__global__ __launch_bounds__(256) void post_kernel(
    const float* __restrict__ rstU, const float* __restrict__ denom,
    const float* __restrict__ bias_gat, const float* __restrict__ W1,
    const float* __restrict__ b1, const float* __restrict__ W2,
    const float* __restrict__ b2, const int* __restrict__ gid,
    float* __restrict__ sums_priv, float* __restrict__ counts_priv, int N)
{
  __shared__ float W1s[64 * 128];
  __shared__ float W2s[128 * 16];
  __shared__ float b1s[128];
  __shared__ float b2s[16];
  __shared__ float h2buf[4][64];
  __shared__ float zbuf[4][128];
  const int tid = threadIdx.x;
#pragma unroll
  for (int q = 0; q < 8; ++q)
    *reinterpret_cast<float4*>(&W1s[(tid + q * 256) * 4]) =
        *reinterpret_cast<const float4*>(&W1[(tid + q * 256) * 4]);
#pragma unroll
  for (int q = 0; q < 2; ++q)
    *reinterpret_cast<float4*>(&W2s[(tid + q * 256) * 4]) =
        *reinterpret_cast<const float4*>(&W2[(tid + q * 256) * 4]);
  if (tid < 128) b1s[tid] = b1[tid];
  if (tid < 16)  b2s[tid] = b2[tid];
  __syncthreads();

  const int wave = tid >> 6, lane = tid & 63;
  const int part = blockIdx.x & (NPART - 1);
  for (int i = 0; i < 8; ++i) {
    int n = blockIdx.x * 32 + wave * 8 + i;
    float h2l = 0.f;
    int g = 0;
    if (n < N) {
      g = gid[n];
      float acc = 0.f;
#pragma unroll
      for (int h = 0; h < 3; ++h) {
        float den = denom[n * 3 + h];
        float inv = den > 0.f ? 1.f / den : 0.f;     // guard 0-in-degree
        float r = rstU[(size_t)n * FDIM + h * 64 + lane] * inv + bias_gat[h * 64 + lane];
        acc += r > 0.f ? r : 0.f;
      }
      h2l = acc * (1.f / 3.f);
    }
    h2buf[wave][lane] = h2l;
    __syncthreads();
    float z0 = b1s[lane], z1 = b1s[lane + 64];
#pragma unroll 8
    for (int k = 0; k < 64; ++k) {
      float hk = h2buf[wave][k];
      z0 += hk * W1s[k * 128 + lane];
      z1 += hk * W1s[k * 128 + lane + 64];
    }
    zbuf[wave][lane]      = z0 > 0.f ? z0 : 0.f;
    zbuf[wave][lane + 64] = z1 > 0.f ? z1 : 0.f;
    __syncthreads();
    if (lane < 16 && n < N) {
      float y = b2s[lane];
#pragma unroll 16
      for (int k = 0; k < 128; ++k) y += zbuf[wave][k] * W2s[k * 16 + lane];
      atomicAdd(&sums_priv[(part * NGRAPH + g) * 16 + lane], y);
    }
    if (lane == 16 && n < N) atomicAdd(&counts_priv[part * NGRAPH + g], 1.f);
    __syncthreads();
  }
}

// ---------------- reduce privatized graph sums -> output --------------------
__global__ void finalize_kernel(const float* __restrict__ sums_priv,
                                const float* __restrict__ counts_priv,
                                float* __restrict__ out)
{
  int j = threadIdx.x;            // 0..1023  (g*16 + col)
  int g = j >> 4;
  float s = 0.f, c = 0.f;
  for (int p = 0; p < NPART; ++p) {
    s += sums_priv[p * NGRAPH * 16 + j];
    c += counts_priv[p * NGRAPH + g];
  }
  out[j] = s / fmaxf(c, 1.f);
}

extern "C" void kernel_launch(void* const* d_in, const int* in_sizes, int n_in,
                              void* d_out, int out_size, void* d_ws, size_t ws_size,
                              hipStream_t stream)
{
  const int*   h0  = (const int*)  d_in[0];
  const int*   src = (const int*)  d_in[1];
  const int*   dst = (const int*)  d_in[2];
  const int*   gid = (const int*)  d_in[3];
  const float* emb = (const float*)d_in[4];
  const float* Wfc = (const float*)d_in[5];
  const float* al  = (const float*)d_in[6];
  const float* ar  = (const float*)d_in[7];
  const float* bg  = (const float*)d_in[8];
  const float* W1  = (const float*)d_in[9];
  const float* b1  = (const float*)d_in[10];
  const float* W2  = (const float*)d_in[11];
  const float* b2  = (const float*)d_in[12];
  float* out = (float*)d_out;

  char* ws = (char*)d_ws;
  size_t off = 0;
  auto alloc = [&](size_t bytes) -> void* {
    off = (off + 255) & ~(size_t)255;
    void* p = ws + off;
    off += bytes;
    return p;
  };
  float* feat  = (float*)alloc((size_t)NNODES * FDIM * 4);
  float* rstU  = (float*)alloc((size_t)NNODES * FDIM * 4);
  float* el    = (float*)alloc((size_t)NNODES * 3 * 4);
  float* er    = (float*)alloc((size_t)NNODES * 3 * 4);
  float* denom = (float*)alloc((size_t)NNODES * 3 * 4);
  float* sums  = (float*)alloc((size_t)NPART * NGRAPH * 16 * 4);
  float* cnts  = (float*)alloc((size_t)NPART * NGRAPH * 4);

  hipMemsetAsync(rstU,  0, (size_t)NNODES * FDIM * 4, stream);
  hipMemsetAsync(denom, 0, (size_t)NNODES * 3 * 4, stream);
  hipMemsetAsync(sums,  0, (size_t)NPART * NGRAPH * 16 * 4, stream);
  hipMemsetAsync(cnts,  0, (size_t)NPART * NGRAPH * 4, stream);

  feat_gemm_kernel<<<(NNODES + 63) / 64, 256, 0, stream>>>(h0, emb, Wfc, feat, NNODES);
  attn_kernel<<<(NNODES + 3) / 4, 256, 0, stream>>>(feat, al, ar, el, er, NNODES);
  edge_kernel<<<2048, 256, 0, stream>>>(src, dst, el, er, feat, denom, rstU, NEDGES);
  post_kernel<<<NNODES / 32, 256, 0, stream>>>(rstU, denom, bg, W1, b1, W2, b2, gid,
                                               sums, cnts, NNODES);
  finalize_kernel<<<1, 1024, 0, stream>>>(sums, cnts, out);
}

// Round 2
// 705.936 us; speedup vs baseline: 2.0807x; 2.0807x over previous
//
#include <hip/hip_runtime.h>
#include <hip/hip_bf16.h>

#define NNODES 100000
#define NEDGES 1600000
#define HDIM 256
#define ADIM 64
#define NHEADS 3
#define FDIM 192   // NHEADS*ADIM
#define NGRAPH 64
#define NPART 64   // privatized partitions for graph-sum atomics

// ---------------- feat = emb[h0] @ W_fc  (fp32 tiled GEMM with A-gather) ----
__global__ __launch_bounds__(256) void feat_gemm_kernel(
    const int* __restrict__ h0, const float* __restrict__ emb,
    const float* __restrict__ Wfc, float* __restrict__ feat, int N)
{
  __shared__ float As[64 * 32];
  __shared__ float Bs[32 * FDIM];
  const int tid = threadIdx.x;
  const int tx = tid & 31;   // col group: cols tx + 32*c
  const int ty = tid >> 5;   // 0..7   : rows ty + 8*j
  const int n0 = blockIdx.x * 64;

  float acc[8][6];
#pragma unroll
  for (int j = 0; j < 8; ++j)
#pragma unroll
    for (int c = 0; c < 6; ++c) acc[j][c] = 0.f;

  for (int k0 = 0; k0 < HDIM; k0 += 32) {
#pragma unroll
    for (int q = 0; q < 2; ++q) {
      int idx = tid * 2 + q;
      int row = idx >> 3;
      int c4  = idx & 7;
      int n = n0 + row;
      float4 v = make_float4(0.f, 0.f, 0.f, 0.f);
      if (n < N) {
        int e = h0[n];
        v = *reinterpret_cast<const float4*>(&emb[(size_t)e * HDIM + k0 + c4 * 4]);
      }
      *reinterpret_cast<float4*>(&As[row * 32 + c4 * 4]) = v;
    }
#pragma unroll
    for (int q = 0; q < 6; ++q) {
      int idx = tid + q * 256;
      int kk = idx / 48;
      int c4 = idx % 48;
      float4 v = *reinterpret_cast<const float4*>(&Wfc[(size_t)(k0 + kk) * FDIM + c4 * 4]);
      *reinterpret_cast<float4*>(&Bs[kk * FDIM + c4 * 4]) = v;
    }
    __syncthreads();
#pragma unroll
    for (int kk = 0; kk < 32; ++kk) {
      float b[6];
#pragma unroll
      for (int c = 0; c < 6; ++c) b[c] = Bs[kk * FDIM + tx + 32 * c];
#pragma unroll
      for (int j = 0; j < 8; ++j) {
        float a = As[(ty + j * 8) * 32 + kk];
#pragma unroll
        for (int c = 0; c < 6; ++c) acc[j][c] += a * b[c];
      }
    }
    __syncthreads();
  }
#pragma unroll
  for (int j = 0; j < 8; ++j) {
    int n = n0 + ty + j * 8;
    if (n < N) {
#pragma unroll
      for (int c = 0; c < 6; ++c)
        feat[(size_t)n * FDIM + tx + 32 * c] = acc[j][c];
    }
  }
}

// ---------------- el/er: per-node attention dots -----------------
__global__ __launch_bounds__(256) void attn_kernel(
    const float* __restrict__ feat, const float* __restrict__ attn_l,
    const float* __restrict__ attn_r, float* __restrict__ el,
    float* __restrict__ er, int N)
{
  int wid  = blockIdx.x * (blockDim.x >> 6) + (threadIdx.x >> 6);
  int lane = threadIdx.x & 63;
  if (wid >= N) return;
  float sl[3], sr[3];
#pragma unroll
  for (int h = 0; h < 3; ++h) {
    float v = feat[(size_t)wid * FDIM + h * 64 + lane];
    sl[h] = v * attn_l[h * 64 + lane];
    sr[h] = v * attn_r[h * 64 + lane];
  }
#pragma unroll
  for (int s = 32; s > 0; s >>= 1) {
#pragma unroll
    for (int h = 0; h < 3; ++h) {
      sl[h] += __shfl_xor(sl[h], s, 64);
      sr[h] += __shfl_xor(sr[h], s, 64);
    }
  }
  if (lane == 0) {
#pragma unroll
    for (int h = 0; h < 3; ++h) { el[wid * 3 + h] = sl[h]; er[wid * 3 + h] = sr[h]; }
  }
}

// ---------------- counting sort by dst: histogram -----------------
__global__ __launch_bounds__(256) void hist_kernel(
    const int* __restrict__ dst, int* __restrict__ cnt, int E)
{
  int e = blockIdx.x * 256 + threadIdx.x;
  if (e < E) atomicAdd(&cnt[dst[e]], 1);
}

// per-block sums (1024 elems / block)
__global__ __launch_bounds__(256) void scan_sum_kernel(
    const int* __restrict__ cnt, int* __restrict__ bsum, int n)
{
  __shared__ int red[256];
  int t = threadIdx.x;
  int base = blockIdx.x * 1024 + t * 4;
  int s = 0;
#pragma unroll
  for (int j = 0; j < 4; ++j) if (base + j < n) s += cnt[base + j];
  red[t] = s;
  __syncthreads();
  for (int o = 128; o > 0; o >>= 1) {
    if (t < o) red[t] += red[t + o];
    __syncthreads();
  }
  if (t == 0) bsum[blockIdx.x] = red[0];
}

__global__ void scan_bsum_kernel(int* bsum, int nb)
{
  if (threadIdx.x == 0 && blockIdx.x == 0) {
    int acc = 0;
    for (int i = 0; i < nb; ++i) { int v = bsum[i]; bsum[i] = acc; acc += v; }
  }
}

__global__ __launch_bounds__(256) void scan_write_kernel(
    const int* __restrict__ cnt, const int* __restrict__ bsum,
    int* __restrict__ offs, int n, int total)
{
  __shared__ int sd[256];
  int t = threadIdx.x;
  int base = blockIdx.x * 1024 + t * 4;
  int c[4];
  int ts = 0;
#pragma unroll
  for (int j = 0; j < 4; ++j) { c[j] = (base + j < n) ? cnt[base + j] : 0; ts += c[j]; }
  sd[t] = ts;
  __syncthreads();
  for (int o = 1; o < 256; o <<= 1) {
    int v = (t >= o) ? sd[t - o] : 0;
    __syncthreads();
    sd[t] += v;
    __syncthreads();
  }
  int run = sd[t] - ts + bsum[blockIdx.x];
#pragma unroll
  for (int j = 0; j < 4; ++j) {
    if (base + j < n) offs[base + j] = run;
    run += c[j];
  }
  if (blockIdx.x == 0 && t == 0) offs[n] = total;
}

// ---------------- scatter edges into dst-sorted records ---------------------
// rec = (src_bits, w0, w1, w2); weights computed once here
__global__ __launch_bounds__(256) void scatter_kernel(
    const int* __restrict__ src, const int* __restrict__ dst,
    const float* __restrict__ el, const float* __restrict__ er,
    const int* __restrict__ offs, int* __restrict__ cursor,
    float4* __restrict__ recs, int E)
{
  int e = blockIdx.x * 256 + threadIdx.x;
  if (e >= E) return;
  int s = src[e], d = dst[e];
  float w[3];
#pragma unroll
  for (int h = 0; h < 3; ++h) {
    float ev = el[s * 3 + h] + er[d * 3 + h];
    ev = ev > 0.f ? ev : 0.2f * ev;   // leaky_relu 0.2
    w[h] = __expf(ev);                // |ev| << 1: no max-shift needed
  }
  int p = offs[d] + atomicAdd(&cursor[d], 1);
  float4 r;
  r.x = __int_as_float(s);
  r.y = w[0]; r.z = w[1]; r.w = w[2];
  recs[p] = r;
}

// ---------------- per-node aggregation (no atomics) + normalize/bias/relu/mean
// one wave per node; lane owns one of 64 'a' slots per head
__global__ __launch_bounds__(256) void aggregate_kernel(
    const float4* __restrict__ recs, const int* __restrict__ offs,
    const float* __restrict__ feat, const float* __restrict__ bias_gat,
    float* __restrict__ h2g, int N)
{
  int lane = threadIdx.x & 63;
  int n = blockIdx.x * 4 + (threadIdx.x >> 6);
  if (n >= N) return;
  int lo = offs[n], hi = offs[n + 1];
  float a0 = 0.f, a1 = 0.f, a2 = 0.f, d0 = 0.f, d1 = 0.f, d2 = 0.f;
  for (int i = lo; i < hi; ++i) {
    float4 r = recs[i];
    int s = __float_as_int(r.x);
    const float* fs = &feat[(size_t)s * FDIM];
    a0 += r.y * fs[lane];
    a1 += r.z * fs[64 + lane];
    a2 += r.w * fs[128 + lane];
    d0 += r.y; d1 += r.z; d2 += r.w;
  }
  float i0 = d0 > 0.f ? 1.f / d0 : 0.f;   // guard 0-in-degree
  float i1 = d1 > 0.f ? 1.f / d1 : 0.f;
  float i2 = d2 > 0.f ? 1.f / d2 : 0.f;
  float r0 = a0 * i0 + bias_gat[lane];
  float r1 = a1 * i1 + bias_gat[64 + lane];
  float r2 = a2 * i2 + bias_gat[128 + lane];
  float h2 = (fmaxf(r0, 0.f) + fmaxf(r1, 0.f) + fmaxf(r2, 0.f)) * (1.f / 3.f);
  h2g[(size_t)n * 64 + lane] = h2;
}

// ---------------- per-node MLP + per-graph privatized sums -------------------
__global__ __launch_bounds__(256) void post_kernel(
    const float* __restrict__ h2g, const float* __restrict__ W1,
    const float* __restrict__ b1, const float* __restrict__ W2,
    const float* __restrict__ b2, const int* __restrict__ gid,
    float* __restrict__ sums_priv, float* __restrict__ counts_priv, int N)
{
  __shared__ float W1s[64 * 128];
  __shared__ float W2s[128 * 16];
  __shared__ float b1s[128];
  __shared__ float b2s[16];
  __shared__ float h2buf[4][64];
  __shared__ float zbuf[4][128];
  const int tid = threadIdx.x;
#pragma unroll
  for (int q = 0; q < 8; ++q)
    *reinterpret_cast<float4*>(&W1s[(tid + q * 256) * 4]) =
        *reinterpret_cast<const float4*>(&W1[(tid + q * 256) * 4]);
#pragma unroll
  for (int q = 0; q < 2; ++q)
    *reinterpret_cast<float4*>(&W2s[(tid + q * 256) * 4]) =
        *reinterpret_cast<const float4*>(&W2[(tid + q * 256) * 4]);
  if (tid < 128) b1s[tid] = b1[tid];
  if (tid < 16)  b2s[tid] = b2[tid];
  __syncthreads();

  const int wave = tid >> 6, lane = tid & 63;
  const int part = blockIdx.x & (NPART - 1);
  for (int i = 0; i < 8; ++i) {
    int n = blockIdx.x * 32 + wave * 8 + i;
    float h2l = 0.f;
    int g = 0;
    if (n < N) {
      g = gid[n];
      h2l = h2g[(size_t)n * 64 + lane];
    }
    h2buf[wave][lane] = h2l;
    __syncthreads();
    float z0 = b1s[lane], z1 = b1s[lane + 64];
#pragma unroll 8
    for (int k = 0; k < 64; ++k) {
      float hk = h2buf[wave][k];
      z0 += hk * W1s[k * 128 + lane];
      z1 += hk * W1s[k * 128 + lane + 64];
    }
    zbuf[wave][lane]      = z0 > 0.f ? z0 : 0.f;
    zbuf[wave][lane + 64] = z1 > 0.f ? z1 : 0.f;
    __syncthreads();
    if (lane < 16 && n < N) {
      float y = b2s[lane];
#pragma unroll 16
      for (int k = 0; k < 128; ++k) y += zbuf[wave][k] * W2s[k * 16 + lane];
      atomicAdd(&sums_priv[(part * NGRAPH + g) * 16 + lane], y);
    }
    if (lane == 16 && n < N) atomicAdd(&counts_priv[part * NGRAPH + g], 1.f);
    __syncthreads();
  }
}

// ---------------- reduce privatized graph sums -> output --------------------
__global__ void finalize_kernel(const float* __restrict__ sums_priv,
                                const float* __restrict__ counts_priv,
                                float* __restrict__ out)
{
  int j = threadIdx.x;            // 0..1023  (g*16 + col)
  int g = j >> 4;
  float s = 0.f, c = 0.f;
  for (int p = 0; p < NPART; ++p) {
    s += sums_priv[p * NGRAPH * 16 + j];
    c += counts_priv[p * NGRAPH + g];
  }
  out[j] = s / fmaxf(c, 1.f);
}

extern "C" void kernel_launch(void* const* d_in, const int* in_sizes, int n_in,
                              void* d_out, int out_size, void* d_ws, size_t ws_size,
                              hipStream_t stream)
{
  const int*   h0  = (const int*)  d_in[0];
  const int*   src = (const int*)  d_in[1];
  const int*   dst = (const int*)  d_in[2];
  const int*   gid = (const int*)  d_in[3];
  const float* emb = (const float*)d_in[4];
  const float* Wfc = (const float*)d_in[5];
  const float* al  = (const float*)d_in[6];
  const float* ar  = (const float*)d_in[7];
  const float* bg  = (const float*)d_in[8];
  const float* W1  = (const float*)d_in[9];
  const float* b1  = (const float*)d_in[10];
  const float* W2  = (const float*)d_in[11];
  const float* b2  = (const float*)d_in[12];
  float* out = (float*)d_out;

  char* ws = (char*)d_ws;
  size_t off = 0;
  auto alloc = [&](size_t bytes) -> void* {
    off = (off + 255) & ~(size_t)255;
    void* p = ws + off;
    off += bytes;
    return p;
  };
  float*  feat   = (float*) alloc((size_t)NNODES * FDIM * 4);
  float4* recs   = (float4*)alloc((size_t)NEDGES * 16);
  float*  h2g    = (float*) alloc((size_t)NNODES * 64 * 4);
  float*  el     = (float*) alloc((size_t)NNODES * 3 * 4);
  float*  er     = (float*) alloc((size_t)NNODES * 3 * 4);
  int*    cnt    = (int*)   alloc((size_t)NNODES * 4);
  int*    offs   = (int*)   alloc((size_t)(NNODES + 1) * 4);
  int*    cursor = (int*)   alloc((size_t)NNODES * 4);
  int*    bsum   = (int*)   alloc((size_t)128 * 4);
  float*  sums   = (float*) alloc((size_t)NPART * NGRAPH * 16 * 4);
  float*  cnts   = (float*) alloc((size_t)NPART * NGRAPH * 4);

  hipMemsetAsync(cnt,    0, (size_t)NNODES * 4, stream);
  hipMemsetAsync(cursor, 0, (size_t)NNODES * 4, stream);
  hipMemsetAsync(sums,   0, (size_t)NPART * NGRAPH * 16 * 4, stream);
  hipMemsetAsync(cnts,   0, (size_t)NPART * NGRAPH * 4, stream);

  const int NB = (NNODES + 1023) / 1024;   // 98

  feat_gemm_kernel<<<(NNODES + 63) / 64, 256, 0, stream>>>(h0, emb, Wfc, feat, NNODES);
  attn_kernel<<<(NNODES + 3) / 4, 256, 0, stream>>>(feat, al, ar, el, er, NNODES);
  hist_kernel<<<(NEDGES + 255) / 256, 256, 0, stream>>>(dst, cnt, NEDGES);
  scan_sum_kernel<<<NB, 256, 0, stream>>>(cnt, bsum, NNODES);
  scan_bsum_kernel<<<1, 64, 0, stream>>>(bsum, NB);
  scan_write_kernel<<<NB, 256, 0, stream>>>(cnt, bsum, offs, NNODES, NEDGES);
  scatter_kernel<<<(NEDGES + 255) / 256, 256, 0, stream>>>(src, dst, el, er, offs,
                                                           cursor, recs, NEDGES);
  aggregate_kernel<<<(NNODES + 3) / 4, 256, 0, stream>>>(recs, offs, feat, bg, h2g, NNODES);
  post_kernel<<<(NNODES + 31) / 32, 256, 0, stream>>>(h2g, W1, b1, W2, b2, gid,
                                                      sums, cnts, NNODES);
  finalize_kernel<<<1, 1024, 0, stream>>>(sums, cnts, out);
}

// Round 3
// 578.641 us; speedup vs baseline: 2.5384x; 1.2200x over previous
//
#include <hip/hip_runtime.h>
#include <hip/hip_bf16.h>

#define NNODES 100000
#define NEDGES 1600000
#define VOCAB 50000
#define HDIM 256
#define ADIM 64
#define NHEADS 3
#define FDIM 192   // NHEADS*ADIM
#define NGRAPH 64
#define NPART 64

typedef __attribute__((ext_vector_type(8))) short bf16x8;  // 8 bf16 = 4 VGPRs
typedef __attribute__((ext_vector_type(4))) float f32x4;

__device__ __forceinline__ float bf2f(unsigned short u) {
  return __uint_as_float((unsigned int)u << 16);
}
__device__ __forceinline__ unsigned short f2bf(float f) {
  unsigned int u = __float_as_uint(f);
  u += 0x7FFFu + ((u >> 16) & 1u);   // round-nearest-even
  return (unsigned short)(u >> 16);
}

// ---------------- fp32 -> bf16 conversions --------------------------------
__global__ __launch_bounds__(256) void conv_emb_kernel(
    const float* __restrict__ emb, unsigned short* __restrict__ emb_bf, int n)
{
  int i = (blockIdx.x * 256 + threadIdx.x) * 4;
  if (i >= n) return;
  float4 v = *reinterpret_cast<const float4*>(&emb[i]);
  ushort4 o;
  o.x = f2bf(v.x); o.y = f2bf(v.y); o.z = f2bf(v.z); o.w = f2bf(v.w);
  *reinterpret_cast<ushort4*>(&emb_bf[i]) = o;
}

// Wt[c][k] = Wfc[k][c]  (transposed, bf16)  c<192, k<256
__global__ __launch_bounds__(256) void conv_w_kernel(
    const float* __restrict__ Wfc, unsigned short* __restrict__ Wt)
{
  int i = blockIdx.x * 256 + threadIdx.x;   // 49152 total
  if (i >= HDIM * FDIM) return;
  int c = i / HDIM, k = i % HDIM;
  Wt[i] = f2bf(Wfc[(size_t)k * FDIM + c]);
}

// ---------------- proj = emb_bf @ Wfc  (bf16 MFMA, LDS-free) ---------------
// block = 4 waves, 64 rows; wave: 16 rows x 192 cols; K=256 in 8 steps of 32
__global__ __launch_bounds__(256) void proj_gemm_kernel(
    const unsigned short* __restrict__ emb_bf,  // [V][256]
    const unsigned short* __restrict__ Wt,      // [192][256]
    unsigned short* __restrict__ proj_bf,       // [V][192]
    int V)
{
  const int wave = threadIdx.x >> 6;
  const int lane = threadIdx.x & 63;
  const int row0 = blockIdx.x * 64 + wave * 16;
  int arow = row0 + (lane & 15);
  if (arow >= V) arow = V - 1;                  // clamp; stores are guarded
  const int kgrp = (lane >> 4) * 8;             // 0,8,16,24

  f32x4 acc[12];
#pragma unroll
  for (int c = 0; c < 12; ++c) acc[c] = (f32x4){0.f, 0.f, 0.f, 0.f};

  const unsigned short* arow_p = &emb_bf[(size_t)arow * HDIM + kgrp];
  const unsigned short* bcol_p = &Wt[(size_t)(lane & 15) * HDIM + kgrp];

#pragma unroll
  for (int ks = 0; ks < 8; ++ks) {
    bf16x8 a = *reinterpret_cast<const bf16x8*>(arow_p + ks * 32);
#pragma unroll
    for (int c = 0; c < 12; ++c) {
      bf16x8 b = *reinterpret_cast<const bf16x8*>(bcol_p + (size_t)c * 16 * HDIM + ks * 32);
      acc[c] = __builtin_amdgcn_mfma_f32_16x16x32_bf16(a, b, acc[c], 0, 0, 0);
    }
  }

  // C/D layout: col = lane&15, row = 4*(lane>>4)+i
  const int cb = lane & 15;
  const int rb = row0 + 4 * (lane >> 4);
#pragma unroll
  for (int i = 0; i < 4; ++i) {
    int r = rb + i;
    if (r < V) {
#pragma unroll
      for (int c = 0; c < 12; ++c)
        proj_bf[(size_t)r * FDIM + c * 16 + cb] = f2bf(acc[c][i]);
    }
  }
}

// ---------------- per-vocab attention dots ---------------------------------
__global__ __launch_bounds__(256) void vattn_kernel(
    const unsigned short* __restrict__ proj_bf, const float* __restrict__ attn_l,
    const float* __restrict__ attn_r, float* __restrict__ elv,
    float* __restrict__ erv, int V)
{
  int v    = blockIdx.x * 4 + (threadIdx.x >> 6);
  int lane = threadIdx.x & 63;
  if (v >= V) return;
  float sl[3], sr[3];
#pragma unroll
  for (int h = 0; h < 3; ++h) {
    float f = bf2f(proj_bf[(size_t)v * FDIM + h * 64 + lane]);
    sl[h] = f * attn_l[h * 64 + lane];
    sr[h] = f * attn_r[h * 64 + lane];
  }
#pragma unroll
  for (int s = 32; s > 0; s >>= 1) {
#pragma unroll
    for (int h = 0; h < 3; ++h) {
      sl[h] += __shfl_xor(sl[h], s, 64);
      sr[h] += __shfl_xor(sr[h], s, 64);
    }
  }
  if (lane == 0) {
#pragma unroll
    for (int h = 0; h < 3; ++h) { elv[v * 3 + h] = sl[h]; erv[v * 3 + h] = sr[h]; }
  }
}

// ---------------- node-level el/er gather -----------------------------------
__global__ __launch_bounds__(256) void ngather_kernel(
    const int* __restrict__ h0, const float* __restrict__ elv,
    const float* __restrict__ erv, float* __restrict__ nel,
    float* __restrict__ ner, int N)
{
  int n = blockIdx.x * 256 + threadIdx.x;
  if (n >= N) return;
  int v = h0[n];
#pragma unroll
  for (int h = 0; h < 3; ++h) {
    nel[n * 3 + h] = elv[v * 3 + h];
    ner[n * 3 + h] = erv[v * 3 + h];
  }
}

// ---------------- counting sort by dst ------------------------------------
__global__ __launch_bounds__(256) void hist_kernel(
    const int* __restrict__ dst, int* __restrict__ cnt, int E)
{
  int e = blockIdx.x * 256 + threadIdx.x;
  if (e < E) atomicAdd(&cnt[dst[e]], 1);
}

__global__ __launch_bounds__(256) void scan_sum_kernel(
    const int* __restrict__ cnt, int* __restrict__ bsum, int n)
{
  __shared__ int red[256];
  int t = threadIdx.x;
  int base = blockIdx.x * 1024 + t * 4;
  int s = 0;
#pragma unroll
  for (int j = 0; j < 4; ++j) if (base + j < n) s += cnt[base + j];
  red[t] = s;
  __syncthreads();
  for (int o = 128; o > 0; o >>= 1) {
    if (t < o) red[t] += red[t + o];
    __syncthreads();
  }
  if (t == 0) bsum[blockIdx.x] = red[0];
}

__global__ void scan_bsum_kernel(int* bsum, int nb)
{
  if (threadIdx.x == 0 && blockIdx.x == 0) {
    int acc = 0;
    for (int i = 0; i < nb; ++i) { int v = bsum[i]; bsum[i] = acc; acc += v; }
  }
}

__global__ __launch_bounds__(256) void scan_write_kernel(
    const int* __restrict__ cnt, const int* __restrict__ bsum,
    int* __restrict__ offs, int n, int total)
{
  __shared__ int sd[256];
  int t = threadIdx.x;
  int base = blockIdx.x * 1024 + t * 4;
  int c[4];
  int ts = 0;
#pragma unroll
  for (int j = 0; j < 4; ++j) { c[j] = (base + j < n) ? cnt[base + j] : 0; ts += c[j]; }
  sd[t] = ts;
  __syncthreads();
  for (int o = 1; o < 256; o <<= 1) {
    int v = (t >= o) ? sd[t - o] : 0;
    __syncthreads();
    sd[t] += v;
    __syncthreads();
  }
  int run = sd[t] - ts + bsum[blockIdx.x];
#pragma unroll
  for (int j = 0; j < 4; ++j) {
    if (base + j < n) offs[base + j] = run;
    run += c[j];
  }
  if (blockIdx.x == 0 && t == 0) offs[n] = total;
}

// ---------------- scatter: rec = (vocab_idx, w0, w1, w2) --------------------
__global__ __launch_bounds__(256) void scatter_kernel(
    const int* __restrict__ src, const int* __restrict__ dst,
    const int* __restrict__ h0,
    const float* __restrict__ nel, const float* __restrict__ ner,
    const int* __restrict__ offs, int* __restrict__ cursor,
    float4* __restrict__ recs, int E)
{
  int e = blockIdx.x * 256 + threadIdx.x;
  if (e >= E) return;
  int s = src[e], d = dst[e];
  float w[3];
#pragma unroll
  for (int h = 0; h < 3; ++h) {
    float ev = nel[s * 3 + h] + ner[d * 3 + h];
    ev = ev > 0.f ? ev : 0.2f * ev;   // leaky_relu 0.2
    w[h] = __expf(ev);                // |ev| << 1: max-shift unnecessary
  }
  int p = offs[d] + atomicAdd(&cursor[d], 1);
  float4 r;
  r.x = __int_as_float(h0[s]);        // vocab index
  r.y = w[0]; r.z = w[1]; r.w = w[2];
  recs[p] = r;
}

// ---------------- per-node aggregation (bf16 proj gathers) ------------------
__global__ __launch_bounds__(256) void aggregate_kernel(
    const float4* __restrict__ recs, const int* __restrict__ offs,
    const unsigned short* __restrict__ proj_bf, const float* __restrict__ bias_gat,
    float* __restrict__ h2g, int N)
{
  int lane = threadIdx.x & 63;
  int n = blockIdx.x * 4 + (threadIdx.x >> 6);
  if (n >= N) return;
  int lo = offs[n], hi = offs[n + 1];
  float a0 = 0.f, a1 = 0.f, a2 = 0.f, d0 = 0.f, d1 = 0.f, d2 = 0.f;
  for (int i = lo; i < hi; ++i) {
    float4 r = recs[i];
    int v = __float_as_int(r.x);
    const unsigned short* ps = &proj_bf[(size_t)v * FDIM];
    a0 += r.y * bf2f(ps[lane]);
    a1 += r.z * bf2f(ps[64 + lane]);
    a2 += r.w * bf2f(ps[128 + lane]);
    d0 += r.y; d1 += r.z; d2 += r.w;
  }
  float i0 = d0 > 0.f ? 1.f / d0 : 0.f;
  float i1 = d1 > 0.f ? 1.f / d1 : 0.f;
  float i2 = d2 > 0.f ? 1.f / d2 : 0.f;
  float r0 = a0 * i0 + bias_gat[lane];
  float r1 = a1 * i1 + bias_gat[64 + lane];
  float r2 = a2 * i2 + bias_gat[128 + lane];
  float h2 = (fmaxf(r0, 0.f) + fmaxf(r1, 0.f) + fmaxf(r2, 0.f)) * (1.f / 3.f);
  h2g[(size_t)n * 64 + lane] = h2;
}

// ---------------- per-node MLP + per-graph privatized sums ------------------
__global__ __launch_bounds__(256) void post_kernel(
    const float* __restrict__ h2g, const float* __restrict__ W1,
    const float* __restrict__ b1, const float* __restrict__ W2,
    const float* __restrict__ b2, const int* __restrict__ gid,
    float* __restrict__ sums_priv, float* __restrict__ counts_priv, int N)
{
  __shared__ float W1s[64 * 128];
  __shared__ float W2s[128 * 16];
  __shared__ float b1s[128];
  __shared__ float b2s[16];
  __shared__ float h2buf[4][64];
  __shared__ float zbuf[4][128];
  const int tid = threadIdx.x;
#pragma unroll
  for (int q = 0; q < 8; ++q)
    *reinterpret_cast<float4*>(&W1s[(tid + q * 256) * 4]) =
        *reinterpret_cast<const float4*>(&W1[(tid + q * 256) * 4]);
#pragma unroll
  for (int q = 0; q < 2; ++q)
    *reinterpret_cast<float4*>(&W2s[(tid + q * 256) * 4]) =
        *reinterpret_cast<const float4*>(&W2[(tid + q * 256) * 4]);
  if (tid < 128) b1s[tid] = b1[tid];
  if (tid < 16)  b2s[tid] = b2[tid];
  __syncthreads();

  const int wave = tid >> 6, lane = tid & 63;
  const int part = blockIdx.x & (NPART - 1);
  for (int i = 0; i < 8; ++i) {
    int n = blockIdx.x * 32 + wave * 8 + i;
    float h2l = 0.f;
    int g = 0;
    if (n < N) {
      g = gid[n];
      h2l = h2g[(size_t)n * 64 + lane];
    }
    h2buf[wave][lane] = h2l;
    __syncthreads();
    float z0 = b1s[lane], z1 = b1s[lane + 64];
#pragma unroll 8
    for (int k = 0; k < 64; ++k) {
      float hk = h2buf[wave][k];
      z0 += hk * W1s[k * 128 + lane];
      z1 += hk * W1s[k * 128 + lane + 64];
    }
    zbuf[wave][lane]      = z0 > 0.f ? z0 : 0.f;
    zbuf[wave][lane + 64] = z1 > 0.f ? z1 : 0.f;
    __syncthreads();
    if (lane < 16 && n < N) {
      float y = b2s[lane];
#pragma unroll 16
      for (int k = 0; k < 128; ++k) y += zbuf[wave][k] * W2s[k * 16 + lane];
      atomicAdd(&sums_priv[(part * NGRAPH + g) * 16 + lane], y);
    }
    if (lane == 16 && n < N) atomicAdd(&counts_priv[part * NGRAPH + g], 1.f);
    __syncthreads();
  }
}

// ---------------- reduce privatized graph sums -> output --------------------
__global__ void finalize_kernel(const float* __restrict__ sums_priv,
                                const float* __restrict__ counts_priv,
                                float* __restrict__ out)
{
  int j = threadIdx.x;            // 0..1023  (g*16 + col)
  int g = j >> 4;
  float s = 0.f, c = 0.f;
  for (int p = 0; p < NPART; ++p) {
    s += sums_priv[p * NGRAPH * 16 + j];
    c += counts_priv[p * NGRAPH + g];
  }
  out[j] = s / fmaxf(c, 1.f);
}

extern "C" void kernel_launch(void* const* d_in, const int* in_sizes, int n_in,
                              void* d_out, int out_size, void* d_ws, size_t ws_size,
                              hipStream_t stream)
{
  const int*   h0  = (const int*)  d_in[0];
  const int*   src = (const int*)  d_in[1];
  const int*   dst = (const int*)  d_in[2];
  const int*   gid = (const int*)  d_in[3];
  const float* emb = (const float*)d_in[4];
  const float* Wfc = (const float*)d_in[5];
  const float* al  = (const float*)d_in[6];
  const float* ar  = (const float*)d_in[7];
  const float* bg  = (const float*)d_in[8];
  const float* W1  = (const float*)d_in[9];
  const float* b1  = (const float*)d_in[10];
  const float* W2  = (const float*)d_in[11];
  const float* b2  = (const float*)d_in[12];
  float* out = (float*)d_out;

  char* ws = (char*)d_ws;
  size_t off = 0;
  auto alloc = [&](size_t bytes) -> void* {
    off = (off + 255) & ~(size_t)255;
    void* p = ws + off;
    off += bytes;
    return p;
  };
  unsigned short* emb_bf  = (unsigned short*)alloc((size_t)VOCAB * HDIM * 2);
  unsigned short* Wt      = (unsigned short*)alloc((size_t)FDIM * HDIM * 2);
  unsigned short* proj_bf = (unsigned short*)alloc((size_t)VOCAB * FDIM * 2);
  float4* recs   = (float4*)alloc((size_t)NEDGES * 16);
  float*  h2g    = (float*) alloc((size_t)NNODES * 64 * 4);
  float*  elv    = (float*) alloc((size_t)VOCAB * 3 * 4);
  float*  erv    = (float*) alloc((size_t)VOCAB * 3 * 4);
  float*  nel    = (float*) alloc((size_t)NNODES * 3 * 4);
  float*  ner    = (float*) alloc((size_t)NNODES * 3 * 4);
  int*    cnt    = (int*)   alloc((size_t)NNODES * 4);
  int*    offs   = (int*)   alloc((size_t)(NNODES + 1) * 4);
  int*    cursor = (int*)   alloc((size_t)NNODES * 4);
  int*    bsum   = (int*)   alloc((size_t)128 * 4);
  float*  sums   = (float*) alloc((size_t)NPART * NGRAPH * 16 * 4);
  float*  cnts   = (float*) alloc((size_t)NPART * NGRAPH * 4);

  hipMemsetAsync(cnt,    0, (size_t)NNODES * 4, stream);
  hipMemsetAsync(cursor, 0, (size_t)NNODES * 4, stream);
  hipMemsetAsync(sums,   0, (size_t)NPART * NGRAPH * 16 * 4, stream);
  hipMemsetAsync(cnts,   0, (size_t)NPART * NGRAPH * 4, stream);

  const int NB = (NNODES + 1023) / 1024;   // 98

  conv_emb_kernel<<<(VOCAB * HDIM / 4 + 255) / 256, 256, 0, stream>>>(
      emb, emb_bf, VOCAB * HDIM);
  conv_w_kernel<<<(HDIM * FDIM + 255) / 256, 256, 0, stream>>>(Wfc, Wt);
  proj_gemm_kernel<<<(VOCAB + 63) / 64, 256, 0, stream>>>(emb_bf, Wt, proj_bf, VOCAB);
  vattn_kernel<<<(VOCAB + 3) / 4, 256, 0, stream>>>(proj_bf, al, ar, elv, erv, VOCAB);
  ngather_kernel<<<(NNODES + 255) / 256, 256, 0, stream>>>(h0, elv, erv, nel, ner, NNODES);
  hist_kernel<<<(NEDGES + 255) / 256, 256, 0, stream>>>(dst, cnt, NEDGES);
  scan_sum_kernel<<<NB, 256, 0, stream>>>(cnt, bsum, NNODES);
  scan_bsum_kernel<<<1, 64, 0, stream>>>(bsum, NB);
  scan_write_kernel<<<NB, 256, 0, stream>>>(cnt, bsum, offs, NNODES, NEDGES);
  scatter_kernel<<<(NEDGES + 255) / 256, 256, 0, stream>>>(src, dst, h0, nel, ner, offs,
                                                           cursor, recs, NEDGES);
  aggregate_kernel<<<(NNODES + 3) / 4, 256, 0, stream>>>(recs, offs, proj_bf, bg,
                                                         h2g, NNODES);
  post_kernel<<<(NNODES + 31) / 32, 256, 0, stream>>>(h2g, W1, b1, W2, b2, gid,
                                                      sums, cnts, NNODES);
  finalize_kernel<<<1, 1024, 0, stream>>>(sums, cnts, out);
}

// Round 4
// 477.608 us; speedup vs baseline: 3.0754x; 1.2115x over previous
//
#include <hip/hip_runtime.h>
#include <hip/hip_bf16.h>

#define NNODES 100000
#define NEDGES 1600000
#define VOCAB 50000
#define HDIM 256
#define ADIM 64
#define NHEADS 3
#define FDIM 192   // NHEADS*ADIM
#define NGRAPH 64
#define NPART 64

typedef __attribute__((ext_vector_type(8))) short bf16x8;  // 8 bf16 = 4 VGPRs
typedef __attribute__((ext_vector_type(4))) float f32x4;

__device__ __forceinline__ float bf2f(unsigned short u) {
  return __uint_as_float((unsigned int)u << 16);
}
__device__ __forceinline__ unsigned short f2bf(float f) {
  unsigned int u = __float_as_uint(f);
  u += 0x7FFFu + ((u >> 16) & 1u);   // round-nearest-even
  return (unsigned short)(u >> 16);
}

// ---------------- fp32 -> bf16 conversions --------------------------------
__global__ __launch_bounds__(256) void conv_emb_kernel(
    const float* __restrict__ emb, unsigned short* __restrict__ emb_bf, int n)
{
  int i = (blockIdx.x * 256 + threadIdx.x) * 4;
  if (i >= n) return;
  float4 v = *reinterpret_cast<const float4*>(&emb[i]);
  ushort4 o;
  o.x = f2bf(v.x); o.y = f2bf(v.y); o.z = f2bf(v.z); o.w = f2bf(v.w);
  *reinterpret_cast<ushort4*>(&emb_bf[i]) = o;
}

// All weight transposes+casts in one launch:
//   Wt [192][256] = Wfc^T ;  W1t [128][64] = W1^T ;  W2t [16][128] = W2^T
__global__ __launch_bounds__(256) void conv_weights_kernel(
    const float* __restrict__ Wfc, const float* __restrict__ W1,
    const float* __restrict__ W2, unsigned short* __restrict__ Wt,
    unsigned short* __restrict__ W1t, unsigned short* __restrict__ W2t)
{
  int i = blockIdx.x * 256 + threadIdx.x;
  if (i < HDIM * FDIM) {
    int c = i / HDIM, k = i % HDIM;
    Wt[i] = f2bf(Wfc[(size_t)k * FDIM + c]);
  } else if (i < HDIM * FDIM + 128 * 64) {
    int j = i - HDIM * FDIM;
    int c = j / 64, k = j % 64;
    W1t[j] = f2bf(W1[(size_t)k * 128 + c]);
  } else if (i < HDIM * FDIM + 128 * 64 + 16 * 128) {
    int j = i - HDIM * FDIM - 128 * 64;
    int c = j / 128, k = j % 128;
    W2t[j] = f2bf(W2[(size_t)k * 16 + c]);
  }
}

// ---------------- proj = emb_bf @ Wfc  (bf16 MFMA, LDS-free) ---------------
__global__ __launch_bounds__(256) void proj_gemm_kernel(
    const unsigned short* __restrict__ emb_bf,  // [V][256]
    const unsigned short* __restrict__ Wt,      // [192][256]
    unsigned short* __restrict__ proj_bf,       // [V][192]
    int V)
{
  const int wave = threadIdx.x >> 6;
  const int lane = threadIdx.x & 63;
  const int row0 = blockIdx.x * 64 + wave * 16;
  int arow = row0 + (lane & 15);
  if (arow >= V) arow = V - 1;
  const int kgrp = (lane >> 4) * 8;

  f32x4 acc[12];
#pragma unroll
  for (int c = 0; c < 12; ++c) acc[c] = (f32x4){0.f, 0.f, 0.f, 0.f};

  const unsigned short* arow_p = &emb_bf[(size_t)arow * HDIM + kgrp];
  const unsigned short* bcol_p = &Wt[(size_t)(lane & 15) * HDIM + kgrp];

#pragma unroll
  for (int ks = 0; ks < 8; ++ks) {
    bf16x8 a = *reinterpret_cast<const bf16x8*>(arow_p + ks * 32);
#pragma unroll
    for (int c = 0; c < 12; ++c) {
      bf16x8 b = *reinterpret_cast<const bf16x8*>(bcol_p + (size_t)c * 16 * HDIM + ks * 32);
      acc[c] = __builtin_amdgcn_mfma_f32_16x16x32_bf16(a, b, acc[c], 0, 0, 0);
    }
  }
  const int cb = lane & 15;
  const int rb = row0 + 4 * (lane >> 4);
#pragma unroll
  for (int i = 0; i < 4; ++i) {
    int r = rb + i;
    if (r < V) {
#pragma unroll
      for (int c = 0; c < 12; ++c)
        proj_bf[(size_t)r * FDIM + c * 16 + cb] = f2bf(acc[c][i]);
    }
  }
}

// ---------------- per-vocab attention dots ---------------------------------
__global__ __launch_bounds__(256) void vattn_kernel(
    const unsigned short* __restrict__ proj_bf, const float* __restrict__ attn_l,
    const float* __restrict__ attn_r, float* __restrict__ elv,
    float* __restrict__ erv, int V)
{
  int v    = blockIdx.x * 4 + (threadIdx.x >> 6);
  int lane = threadIdx.x & 63;
  if (v >= V) return;
  float sl[3], sr[3];
#pragma unroll
  for (int h = 0; h < 3; ++h) {
    float f = bf2f(proj_bf[(size_t)v * FDIM + h * 64 + lane]);
    sl[h] = f * attn_l[h * 64 + lane];
    sr[h] = f * attn_r[h * 64 + lane];
  }
#pragma unroll
  for (int s = 32; s > 0; s >>= 1) {
#pragma unroll
    for (int h = 0; h < 3; ++h) {
      sl[h] += __shfl_xor(sl[h], s, 64);
      sr[h] += __shfl_xor(sr[h], s, 64);
    }
  }
  if (lane == 0) {
#pragma unroll
    for (int h = 0; h < 3; ++h) { elv[v * 3 + h] = sl[h]; erv[v * 3 + h] = sr[h]; }
  }
}

// ---------------- node-level el/er gather -----------------------------------
__global__ __launch_bounds__(256) void ngather_kernel(
    const int* __restrict__ h0, const float* __restrict__ elv,
    const float* __restrict__ erv, float* __restrict__ nel,
    float* __restrict__ ner, int N)
{
  int n = blockIdx.x * 256 + threadIdx.x;
  if (n >= N) return;
  int v = h0[n];
#pragma unroll
  for (int h = 0; h < 3; ++h) {
    nel[n * 3 + h] = elv[v * 3 + h];
    ner[n * 3 + h] = erv[v * 3 + h];
  }
}

// ---------------- counting sort by dst ------------------------------------
__global__ __launch_bounds__(256) void hist_kernel(
    const int* __restrict__ dst, int* __restrict__ cnt, int E)
{
  int e = blockIdx.x * 256 + threadIdx.x;
  if (e < E) atomicAdd(&cnt[dst[e]], 1);
}

__global__ __launch_bounds__(256) void scan_sum_kernel(
    const int* __restrict__ cnt, int* __restrict__ bsum, int n)
{
  __shared__ int red[256];
  int t = threadIdx.x;
  int base = blockIdx.x * 1024 + t * 4;
  int s = 0;
#pragma unroll
  for (int j = 0; j < 4; ++j) if (base + j < n) s += cnt[base + j];
  red[t] = s;
  __syncthreads();
  for (int o = 128; o > 0; o >>= 1) {
    if (t < o) red[t] += red[t + o];
    __syncthreads();
  }
  if (t == 0) bsum[blockIdx.x] = red[0];
}

__global__ void scan_bsum_kernel(int* bsum, int nb)
{
  if (threadIdx.x == 0 && blockIdx.x == 0) {
    int acc = 0;
    for (int i = 0; i < nb; ++i) { int v = bsum[i]; bsum[i] = acc; acc += v; }
  }
}

__global__ __launch_bounds__(256) void scan_write_kernel(
    const int* __restrict__ cnt, const int* __restrict__ bsum,
    int* __restrict__ offs, int n, int total)
{
  __shared__ int sd[256];
  int t = threadIdx.x;
  int base = blockIdx.x * 1024 + t * 4;
  int c[4];
  int ts = 0;
#pragma unroll
  for (int j = 0; j < 4; ++j) { c[j] = (base + j < n) ? cnt[base + j] : 0; ts += c[j]; }
  sd[t] = ts;
  __syncthreads();
  for (int o = 1; o < 256; o <<= 1) {
    int v = (t >= o) ? sd[t - o] : 0;
    __syncthreads();
    sd[t] += v;
    __syncthreads();
  }
  int run = sd[t] - ts + bsum[blockIdx.x];
#pragma unroll
  for (int j = 0; j < 4; ++j) {
    if (base + j < n) offs[base + j] = run;
    run += c[j];
  }
  if (blockIdx.x == 0 && t == 0) offs[n] = total;
}

// ---------------- scatter: rec = (vocab_idx, w0, w1, w2) --------------------
__global__ __launch_bounds__(256) void scatter_kernel(
    const int* __restrict__ src, const int* __restrict__ dst,
    const int* __restrict__ h0,
    const float* __restrict__ nel, const float* __restrict__ ner,
    const int* __restrict__ offs, int* __restrict__ cursor,
    float4* __restrict__ recs, int E)
{
  int e = blockIdx.x * 256 + threadIdx.x;
  if (e >= E) return;
  int s = src[e], d = dst[e];
  float w[3];
#pragma unroll
  for (int h = 0; h < 3; ++h) {
    float ev = nel[s * 3 + h] + ner[d * 3 + h];
    ev = ev > 0.f ? ev : 0.2f * ev;   // leaky_relu 0.2
    w[h] = __expf(ev);                // |ev| << 1: max-shift unnecessary
  }
  int p = offs[d] + atomicAdd(&cursor[d], 1);
  float4 r;
  r.x = __int_as_float(h0[s]);        // vocab index
  r.y = w[0]; r.z = w[1]; r.w = w[2];
  recs[p] = r;
}

// ---------------- per-node aggregation (bf16 proj gathers) -> h2 bf16 -------
__global__ __launch_bounds__(256) void aggregate_kernel(
    const float4* __restrict__ recs, const int* __restrict__ offs,
    const unsigned short* __restrict__ proj_bf, const float* __restrict__ bias_gat,
    unsigned short* __restrict__ h2bf, int N)
{
  int lane = threadIdx.x & 63;
  int n = blockIdx.x * 4 + (threadIdx.x >> 6);
  if (n >= N) return;
  int lo = offs[n], hi = offs[n + 1];
  float a0 = 0.f, a1 = 0.f, a2 = 0.f, d0 = 0.f, d1 = 0.f, d2 = 0.f;
  for (int i = lo; i < hi; ++i) {
    float4 r = recs[i];
    int v = __float_as_int(r.x);
    const unsigned short* ps = &proj_bf[(size_t)v * FDIM];
    a0 += r.y * bf2f(ps[lane]);
    a1 += r.z * bf2f(ps[64 + lane]);
    a2 += r.w * bf2f(ps[128 + lane]);
    d0 += r.y; d1 += r.z; d2 += r.w;
  }
  float i0 = d0 > 0.f ? 1.f / d0 : 0.f;
  float i1 = d1 > 0.f ? 1.f / d1 : 0.f;
  float i2 = d2 > 0.f ? 1.f / d2 : 0.f;
  float r0 = a0 * i0 + bias_gat[lane];
  float r1 = a1 * i1 + bias_gat[64 + lane];
  float r2 = a2 * i2 + bias_gat[128 + lane];
  float h2 = (fmaxf(r0, 0.f) + fmaxf(r1, 0.f) + fmaxf(r2, 0.f)) * (1.f / 3.f);
  h2bf[(size_t)n * 64 + lane] = f2bf(h2);
}

// ---------------- MLP via MFMA: relu(h2@W1+b1)@W2+b2 + graph atomics --------
// block = 4 waves = 64 rows; wave: 16 rows. GEMM1 16x128 K=64, GEMM2 16x16 K=128
__global__ __launch_bounds__(256) void post_mfma_kernel(
    const unsigned short* __restrict__ h2bf,   // [N][64]
    const unsigned short* __restrict__ W1t,    // [128][64]
    const float* __restrict__ b1,
    const unsigned short* __restrict__ W2t,    // [16][128]
    const float* __restrict__ b2, const int* __restrict__ gid,
    float* __restrict__ sums_priv, float* __restrict__ counts_priv, int N)
{
  __shared__ unsigned short z_lds[64 * 128];
  const int wave = threadIdx.x >> 6;
  const int lane = threadIdx.x & 63;
  const int r = lane & 15;
  const int q = lane >> 4;
  const int kg = q * 8;
  const int rw0 = blockIdx.x * 64 + wave * 16;

  int arow = rw0 + r;
  if (arow >= N) arow = N - 1;       // clamp loads; stores guarded

  f32x4 acc1[8];
#pragma unroll
  for (int c = 0; c < 8; ++c) acc1[c] = (f32x4){0.f, 0.f, 0.f, 0.f};

#pragma unroll
  for (int ks = 0; ks < 2; ++ks) {
    bf16x8 a = *reinterpret_cast<const bf16x8*>(&h2bf[(size_t)arow * 64 + kg + ks * 32]);
#pragma unroll
    for (int c = 0; c < 8; ++c) {
      bf16x8 b = *reinterpret_cast<const bf16x8*>(&W1t[(size_t)(c * 16 + r) * 64 + kg + ks * 32]);
      acc1[c] = __builtin_amdgcn_mfma_f32_16x16x32_bf16(a, b, acc1[c], 0, 0, 0);
    }
  }
  // + b1, relu, park z tile in LDS as bf16 (rows are wave-private)
#pragma unroll
  for (int c = 0; c < 8; ++c) {
    float bb = b1[c * 16 + r];
#pragma unroll
    for (int i = 0; i < 4; ++i) {
      float z = acc1[c][i] + bb;
      z = z > 0.f ? z : 0.f;
      z_lds[(wave * 16 + 4 * q + i) * 128 + c * 16 + r] = f2bf(z);
    }
  }
  __syncthreads();

  f32x4 acc2 = (f32x4){0.f, 0.f, 0.f, 0.f};
#pragma unroll
  for (int ks = 0; ks < 4; ++ks) {
    bf16x8 a = *reinterpret_cast<const bf16x8*>(&z_lds[(wave * 16 + r) * 128 + kg + ks * 32]);
    bf16x8 b = *reinterpret_cast<const bf16x8*>(&W2t[(size_t)r * 128 + kg + ks * 32]);
    acc2 = __builtin_amdgcn_mfma_f32_16x16x32_bf16(a, b, acc2, 0, 0, 0);
  }
  const int part = blockIdx.x & (NPART - 1);
  float bb2 = b2[r];
#pragma unroll
  for (int i = 0; i < 4; ++i) {
    int row = rw0 + 4 * q + i;
    if (row < N) {
      int g = gid[row];
      atomicAdd(&sums_priv[(part * NGRAPH + g) * 16 + r], acc2[i] + bb2);
      if (r == 0) atomicAdd(&counts_priv[part * NGRAPH + g], 1.f);
    }
  }
}

// ---------------- reduce privatized graph sums -> output --------------------
__global__ void finalize_kernel(const float* __restrict__ sums_priv,
                                const float* __restrict__ counts_priv,
                                float* __restrict__ out)
{
  int j = threadIdx.x;            // 0..1023  (g*16 + col)
  int g = j >> 4;
  float s = 0.f, c = 0.f;
  for (int p = 0; p < NPART; ++p) {
    s += sums_priv[p * NGRAPH * 16 + j];
    c += counts_priv[p * NGRAPH + g];
  }
  out[j] = s / fmaxf(c, 1.f);
}

extern "C" void kernel_launch(void* const* d_in, const int* in_sizes, int n_in,
                              void* d_out, int out_size, void* d_ws, size_t ws_size,
                              hipStream_t stream)
{
  const int*   h0  = (const int*)  d_in[0];
  const int*   src = (const int*)  d_in[1];
  const int*   dst = (const int*)  d_in[2];
  const int*   gid = (const int*)  d_in[3];
  const float* emb = (const float*)d_in[4];
  const float* Wfc = (const float*)d_in[5];
  const float* al  = (const float*)d_in[6];
  const float* ar  = (const float*)d_in[7];
  const float* bg  = (const float*)d_in[8];
  const float* W1  = (const float*)d_in[9];
  const float* b1  = (const float*)d_in[10];
  const float* W2  = (const float*)d_in[11];
  const float* b2  = (const float*)d_in[12];
  float* out = (float*)d_out;

  char* ws = (char*)d_ws;
  size_t off = 0;
  auto alloc = [&](size_t bytes) -> void* {
    off = (off + 255) & ~(size_t)255;
    void* p = ws + off;
    off += bytes;
    return p;
  };
  unsigned short* emb_bf  = (unsigned short*)alloc((size_t)VOCAB * HDIM * 2);
  unsigned short* Wt      = (unsigned short*)alloc((size_t)FDIM * HDIM * 2);
  unsigned short* W1t     = (unsigned short*)alloc((size_t)128 * 64 * 2);
  unsigned short* W2t     = (unsigned short*)alloc((size_t)16 * 128 * 2);
  unsigned short* proj_bf = (unsigned short*)alloc((size_t)VOCAB * FDIM * 2);
  unsigned short* h2bf    = (unsigned short*)alloc((size_t)NNODES * 64 * 2);
  float4* recs   = (float4*)alloc((size_t)NEDGES * 16);
  float*  elv    = (float*) alloc((size_t)VOCAB * 3 * 4);
  float*  erv    = (float*) alloc((size_t)VOCAB * 3 * 4);
  float*  nel    = (float*) alloc((size_t)NNODES * 3 * 4);
  float*  ner    = (float*) alloc((size_t)NNODES * 3 * 4);
  int*    cnt    = (int*)   alloc((size_t)NNODES * 4);
  int*    offs   = (int*)   alloc((size_t)(NNODES + 1) * 4);
  int*    cursor = (int*)   alloc((size_t)NNODES * 4);
  int*    bsum   = (int*)   alloc((size_t)128 * 4);
  float*  sums   = (float*) alloc((size_t)NPART * NGRAPH * 16 * 4);
  float*  cnts   = (float*) alloc((size_t)NPART * NGRAPH * 4);

  hipMemsetAsync(cnt,    0, (size_t)NNODES * 4, stream);
  hipMemsetAsync(cursor, 0, (size_t)NNODES * 4, stream);
  hipMemsetAsync(sums,   0, (size_t)NPART * NGRAPH * 16 * 4, stream);
  hipMemsetAsync(cnts,   0, (size_t)NPART * NGRAPH * 4, stream);

  const int NB = (NNODES + 1023) / 1024;   // 98

  conv_emb_kernel<<<(VOCAB * HDIM / 4 + 255) / 256, 256, 0, stream>>>(
      emb, emb_bf, VOCAB * HDIM);
  conv_weights_kernel<<<(HDIM * FDIM + 128 * 64 + 16 * 128 + 255) / 256, 256, 0, stream>>>(
      Wfc, W1, W2, Wt, W1t, W2t);
  proj_gemm_kernel<<<(VOCAB + 63) / 64, 256, 0, stream>>>(emb_bf, Wt, proj_bf, VOCAB);
  vattn_kernel<<<(VOCAB + 3) / 4, 256, 0, stream>>>(proj_bf, al, ar, elv, erv, VOCAB);
  ngather_kernel<<<(NNODES + 255) / 256, 256, 0, stream>>>(h0, elv, erv, nel, ner, NNODES);
  hist_kernel<<<(NEDGES + 255) / 256, 256, 0, stream>>>(dst, cnt, NEDGES);
  scan_sum_kernel<<<NB, 256, 0, stream>>>(cnt, bsum, NNODES);
  scan_bsum_kernel<<<1, 64, 0, stream>>>(bsum, NB);
  scan_write_kernel<<<NB, 256, 0, stream>>>(cnt, bsum, offs, NNODES, NEDGES);
  scatter_kernel<<<(NEDGES + 255) / 256, 256, 0, stream>>>(src, dst, h0, nel, ner, offs,
                                                           cursor, recs, NEDGES);
  aggregate_kernel<<<(NNODES + 3) / 4, 256, 0, stream>>>(recs, offs, proj_bf, bg,
                                                         h2bf, NNODES);
  post_mfma_kernel<<<(NNODES + 63) / 64, 256, 0, stream>>>(h2bf, W1t, b1, W2t, b2, gid,
                                                           sums, cnts, NNODES);
  finalize_kernel<<<1, 1024, 0, stream>>>(sums, cnts, out);
}

// Round 5
// 393.187 us; speedup vs baseline: 3.7358x; 1.2147x over previous
//
#include <hip/hip_runtime.h>
#include <hip/hip_bf16.h>

#define NNODES 100000
#define NEDGES 1600000
#define VOCAB 50000
#define HDIM 256
#define ADIM 64
#define NHEADS 3
#define FDIM 192   // NHEADS*ADIM
#define NGRAPH 64
#define NPART 64

typedef __attribute__((ext_vector_type(8))) short bf16x8;  // 8 bf16 = 4 VGPRs
typedef __attribute__((ext_vector_type(4))) float f32x4;

__device__ __forceinline__ float bf2f(unsigned short u) {
  return __uint_as_float((unsigned int)u << 16);
}
__device__ __forceinline__ unsigned short f2bf(float f) {
  unsigned int u = __float_as_uint(f);
  u += 0x7FFFu + ((u >> 16) & 1u);   // round-nearest-even
  return (unsigned short)(u >> 16);
}

// ---------------- fp32 -> bf16 conversions --------------------------------
__global__ __launch_bounds__(256) void conv_emb_kernel(
    const float* __restrict__ emb, unsigned short* __restrict__ emb_bf, int n)
{
  int i = (blockIdx.x * 256 + threadIdx.x) * 4;
  if (i >= n) return;
  float4 v = *reinterpret_cast<const float4*>(&emb[i]);
  ushort4 o;
  o.x = f2bf(v.x); o.y = f2bf(v.y); o.z = f2bf(v.z); o.w = f2bf(v.w);
  *reinterpret_cast<ushort4*>(&emb_bf[i]) = o;
}

// All weight transposes+casts in one launch:
//   Wt [192][256] = Wfc^T ;  W1t [128][64] = W1^T ;  W2t [16][128] = W2^T
__global__ __launch_bounds__(256) void conv_weights_kernel(
    const float* __restrict__ Wfc, const float* __restrict__ W1,
    const float* __restrict__ W2, unsigned short* __restrict__ Wt,
    unsigned short* __restrict__ W1t, unsigned short* __restrict__ W2t)
{
  int i = blockIdx.x * 256 + threadIdx.x;
  if (i < HDIM * FDIM) {
    int c = i / HDIM, k = i % HDIM;
    Wt[i] = f2bf(Wfc[(size_t)k * FDIM + c]);
  } else if (i < HDIM * FDIM + 128 * 64) {
    int j = i - HDIM * FDIM;
    int c = j / 64, k = j % 64;
    W1t[j] = f2bf(W1[(size_t)k * 128 + c]);
  } else if (i < HDIM * FDIM + 128 * 64 + 16 * 128) {
    int j = i - HDIM * FDIM - 128 * 64;
    int c = j / 128, k = j % 128;
    W2t[j] = f2bf(W2[(size_t)k * 16 + c]);
  }
}

// ---------------- proj = emb_bf @ Wfc  (bf16 MFMA, LDS-free) ---------------
__global__ __launch_bounds__(256) void proj_gemm_kernel(
    const unsigned short* __restrict__ emb_bf,  // [V][256]
    const unsigned short* __restrict__ Wt,      // [192][256]
    unsigned short* __restrict__ proj_bf,       // [V][192]
    int V)
{
  const int wave = threadIdx.x >> 6;
  const int lane = threadIdx.x & 63;
  const int row0 = blockIdx.x * 64 + wave * 16;
  int arow = row0 + (lane & 15);
  if (arow >= V) arow = V - 1;
  const int kgrp = (lane >> 4) * 8;

  f32x4 acc[12];
#pragma unroll
  for (int c = 0; c < 12; ++c) acc[c] = (f32x4){0.f, 0.f, 0.f, 0.f};

  const unsigned short* arow_p = &emb_bf[(size_t)arow * HDIM + kgrp];
  const unsigned short* bcol_p = &Wt[(size_t)(lane & 15) * HDIM + kgrp];

#pragma unroll
  for (int ks = 0; ks < 8; ++ks) {
    bf16x8 a = *reinterpret_cast<const bf16x8*>(arow_p + ks * 32);
#pragma unroll
    for (int c = 0; c < 12; ++c) {
      bf16x8 b = *reinterpret_cast<const bf16x8*>(bcol_p + (size_t)c * 16 * HDIM + ks * 32);
      acc[c] = __builtin_amdgcn_mfma_f32_16x16x32_bf16(a, b, acc[c], 0, 0, 0);
    }
  }
  const int cb = lane & 15;
  const int rb = row0 + 4 * (lane >> 4);
#pragma unroll
  for (int i = 0; i < 4; ++i) {
    int r = rb + i;
    if (r < V) {
#pragma unroll
      for (int c = 0; c < 12; ++c)
        proj_bf[(size_t)r * FDIM + c * 16 + cb] = f2bf(acc[c][i]);
    }
  }
}

// ---------------- per-vocab attention dots ---------------------------------
__global__ __launch_bounds__(256) void vattn_kernel(
    const unsigned short* __restrict__ proj_bf, const float* __restrict__ attn_l,
    const float* __restrict__ attn_r, float* __restrict__ elv,
    float* __restrict__ erv, int V)
{
  int v    = blockIdx.x * 4 + (threadIdx.x >> 6);
  int lane = threadIdx.x & 63;
  if (v >= V) return;
  float sl[3], sr[3];
#pragma unroll
  for (int h = 0; h < 3; ++h) {
    float f = bf2f(proj_bf[(size_t)v * FDIM + h * 64 + lane]);
    sl[h] = f * attn_l[h * 64 + lane];
    sr[h] = f * attn_r[h * 64 + lane];
  }
#pragma unroll
  for (int s = 32; s > 0; s >>= 1) {
#pragma unroll
    for (int h = 0; h < 3; ++h) {
      sl[h] += __shfl_xor(sl[h], s, 64);
      sr[h] += __shfl_xor(sr[h], s, 64);
    }
  }
  if (lane == 0) {
#pragma unroll
    for (int h = 0; h < 3; ++h) { elv[v * 3 + h] = sl[h]; erv[v * 3 + h] = sr[h]; }
  }
}

// ---------------- node-level el/er gather -----------------------------------
__global__ __launch_bounds__(256) void ngather_kernel(
    const int* __restrict__ h0, const float* __restrict__ elv,
    const float* __restrict__ erv, float* __restrict__ nel,
    float* __restrict__ ner, int N)
{
  int n = blockIdx.x * 256 + threadIdx.x;
  if (n >= N) return;
  int v = h0[n];
#pragma unroll
  for (int h = 0; h < 3; ++h) {
    nel[n * 3 + h] = elv[v * 3 + h];
    ner[n * 3 + h] = erv[v * 3 + h];
  }
}

// ---------------- counting sort by dst ------------------------------------
__global__ __launch_bounds__(256) void hist_kernel(
    const int* __restrict__ dst, int* __restrict__ cnt, int E)
{
  int e = blockIdx.x * 256 + threadIdx.x;
  if (e < E) atomicAdd(&cnt[dst[e]], 1);
}

__global__ __launch_bounds__(256) void scan_sum_kernel(
    const int* __restrict__ cnt, int* __restrict__ bsum, int n)
{
  __shared__ int red[256];
  int t = threadIdx.x;
  int base = blockIdx.x * 1024 + t * 4;
  int s = 0;
#pragma unroll
  for (int j = 0; j < 4; ++j) if (base + j < n) s += cnt[base + j];
  red[t] = s;
  __syncthreads();
  for (int o = 128; o > 0; o >>= 1) {
    if (t < o) red[t] += red[t + o];
    __syncthreads();
  }
  if (t == 0) bsum[blockIdx.x] = red[0];
}

__global__ void scan_bsum_kernel(int* bsum, int nb)
{
  if (threadIdx.x == 0 && blockIdx.x == 0) {
    int acc = 0;
    for (int i = 0; i < nb; ++i) { int v = bsum[i]; bsum[i] = acc; acc += v; }
  }
}

__global__ __launch_bounds__(256) void scan_write_kernel(
    const int* __restrict__ cnt, const int* __restrict__ bsum,
    int* __restrict__ offs, int n, int total)
{
  __shared__ int sd[256];
  int t = threadIdx.x;
  int base = blockIdx.x * 1024 + t * 4;
  int c[4];
  int ts = 0;
#pragma unroll
  for (int j = 0; j < 4; ++j) { c[j] = (base + j < n) ? cnt[base + j] : 0; ts += c[j]; }
  sd[t] = ts;
  __syncthreads();
  for (int o = 1; o < 256; o <<= 1) {
    int v = (t >= o) ? sd[t - o] : 0;
    __syncthreads();
    sd[t] += v;
    __syncthreads();
  }
  int run = sd[t] - ts + bsum[blockIdx.x];
#pragma unroll
  for (int j = 0; j < 4; ++j) {
    if (base + j < n) offs[base + j] = run;
    run += c[j];
  }
  if (blockIdx.x == 0 && t == 0) offs[n] = total;
}

// ---------------- scatter: rec = 8B (vocab u16 | w0 bf16, w1 bf16 | w2 bf16) -
__global__ __launch_bounds__(256) void scatter_kernel(
    const int* __restrict__ src, const int* __restrict__ dst,
    const int* __restrict__ h0,
    const float* __restrict__ nel, const float* __restrict__ ner,
    const int* __restrict__ offs, int* __restrict__ cursor,
    uint2* __restrict__ recs, int E)
{
  int e = blockIdx.x * 256 + threadIdx.x;
  if (e >= E) return;
  int s = src[e], d = dst[e];
  float w[3];
#pragma unroll
  for (int h = 0; h < 3; ++h) {
    float ev = nel[s * 3 + h] + ner[d * 3 + h];
    ev = ev > 0.f ? ev : 0.2f * ev;   // leaky_relu 0.2
    w[h] = __expf(ev);                // |ev| << 1: max-shift unnecessary
  }
  int p = offs[d] + atomicAdd(&cursor[d], 1);
  uint2 r;
  r.x = (unsigned)h0[s] | ((unsigned)f2bf(w[0]) << 16);   // vocab < 65536
  r.y = (unsigned)f2bf(w[1]) | ((unsigned)f2bf(w[2]) << 16);
  recs[p] = r;
}

// ---------------- per-node aggregation, 4-wide edge batching ---------------
__global__ __launch_bounds__(256) void aggregate_kernel(
    const uint2* __restrict__ recs, const int* __restrict__ offs,
    const unsigned short* __restrict__ proj_bf, const float* __restrict__ bias_gat,
    unsigned short* __restrict__ h2bf, int N)
{
  int lane = threadIdx.x & 63;
  int n = blockIdx.x * 4 + (threadIdx.x >> 6);
  if (n >= N) return;
  int lo = offs[n], hi = offs[n + 1];
  float a0 = 0.f, a1 = 0.f, a2 = 0.f, d0 = 0.f, d1 = 0.f, d2 = 0.f;

  int i = lo;
  for (; i + 4 <= hi; i += 4) {
    uint2 r[4];
#pragma unroll
    for (int j = 0; j < 4; ++j) r[j] = recs[i + j];
    const unsigned short* ps[4];
#pragma unroll
    for (int j = 0; j < 4; ++j)
      ps[j] = &proj_bf[(size_t)(r[j].x & 0xFFFFu) * FDIM];
    float g0[4], g1[4], g2[4];
#pragma unroll
    for (int j = 0; j < 4; ++j) {       // 12 independent gathers in flight
      g0[j] = bf2f(ps[j][lane]);
      g1[j] = bf2f(ps[j][64 + lane]);
      g2[j] = bf2f(ps[j][128 + lane]);
    }
#pragma unroll
    for (int j = 0; j < 4; ++j) {
      float w0 = bf2f((unsigned short)(r[j].x >> 16));
      float w1 = bf2f((unsigned short)(r[j].y & 0xFFFFu));
      float w2 = bf2f((unsigned short)(r[j].y >> 16));
      a0 += w0 * g0[j]; a1 += w1 * g1[j]; a2 += w2 * g2[j];
      d0 += w0; d1 += w1; d2 += w2;
    }
  }
  for (; i < hi; ++i) {
    uint2 r = recs[i];
    const unsigned short* ps = &proj_bf[(size_t)(r.x & 0xFFFFu) * FDIM];
    float w0 = bf2f((unsigned short)(r.x >> 16));
    float w1 = bf2f((unsigned short)(r.y & 0xFFFFu));
    float w2 = bf2f((unsigned short)(r.y >> 16));
    a0 += w0 * bf2f(ps[lane]);
    a1 += w1 * bf2f(ps[64 + lane]);
    a2 += w2 * bf2f(ps[128 + lane]);
    d0 += w0; d1 += w1; d2 += w2;
  }

  float i0 = d0 > 0.f ? 1.f / d0 : 0.f;
  float i1 = d1 > 0.f ? 1.f / d1 : 0.f;
  float i2 = d2 > 0.f ? 1.f / d2 : 0.f;
  float r0 = a0 * i0 + bias_gat[lane];
  float r1 = a1 * i1 + bias_gat[64 + lane];
  float r2 = a2 * i2 + bias_gat[128 + lane];
  float h2 = (fmaxf(r0, 0.f) + fmaxf(r1, 0.f) + fmaxf(r2, 0.f)) * (1.f / 3.f);
  h2bf[(size_t)n * 64 + lane] = f2bf(h2);
}

// ---------------- MLP via MFMA: relu(h2@W1+b1)@W2+b2 + graph atomics --------
__global__ __launch_bounds__(256) void post_mfma_kernel(
    const unsigned short* __restrict__ h2bf,   // [N][64]
    const unsigned short* __restrict__ W1t,    // [128][64]
    const float* __restrict__ b1,
    const unsigned short* __restrict__ W2t,    // [16][128]
    const float* __restrict__ b2, const int* __restrict__ gid,
    float* __restrict__ sums_priv, float* __restrict__ counts_priv, int N)
{
  __shared__ unsigned short z_lds[64 * 128];
  const int wave = threadIdx.x >> 6;
  const int lane = threadIdx.x & 63;
  const int r = lane & 15;
  const int q = lane >> 4;
  const int kg = q * 8;
  const int rw0 = blockIdx.x * 64 + wave * 16;

  int arow = rw0 + r;
  if (arow >= N) arow = N - 1;       // clamp loads; stores guarded

  f32x4 acc1[8];
#pragma unroll
  for (int c = 0; c < 8; ++c) acc1[c] = (f32x4){0.f, 0.f, 0.f, 0.f};

#pragma unroll
  for (int ks = 0; ks < 2; ++ks) {
    bf16x8 a = *reinterpret_cast<const bf16x8*>(&h2bf[(size_t)arow * 64 + kg + ks * 32]);
#pragma unroll
    for (int c = 0; c < 8; ++c) {
      bf16x8 b = *reinterpret_cast<const bf16x8*>(&W1t[(size_t)(c * 16 + r) * 64 + kg + ks * 32]);
      acc1[c] = __builtin_amdgcn_mfma_f32_16x16x32_bf16(a, b, acc1[c], 0, 0, 0);
    }
  }
#pragma unroll
  for (int c = 0; c < 8; ++c) {
    float bb = b1[c * 16 + r];
#pragma unroll
    for (int i = 0; i < 4; ++i) {
      float z = acc1[c][i] + bb;
      z = z > 0.f ? z : 0.f;
      z_lds[(wave * 16 + 4 * q + i) * 128 + c * 16 + r] = f2bf(z);
    }
  }
  __syncthreads();

  f32x4 acc2 = (f32x4){0.f, 0.f, 0.f, 0.f};
#pragma unroll
  for (int ks = 0; ks < 4; ++ks) {
    bf16x8 a = *reinterpret_cast<const bf16x8*>(&z_lds[(wave * 16 + r) * 128 + kg + ks * 32]);
    bf16x8 b = *reinterpret_cast<const bf16x8*>(&W2t[(size_t)r * 128 + kg + ks * 32]);
    acc2 = __builtin_amdgcn_mfma_f32_16x16x32_bf16(a, b, acc2, 0, 0, 0);
  }
  const int part = blockIdx.x & (NPART - 1);
  float bb2 = b2[r];
#pragma unroll
  for (int i = 0; i < 4; ++i) {
    int row = rw0 + 4 * q + i;
    if (row < N) {
      int g = gid[row];
      atomicAdd(&sums_priv[(part * NGRAPH + g) * 16 + r], acc2[i] + bb2);
      if (r == 0) atomicAdd(&counts_priv[part * NGRAPH + g], 1.f);
    }
  }
}

// ---------------- reduce privatized graph sums -> output --------------------
__global__ void finalize_kernel(const float* __restrict__ sums_priv,
                                const float* __restrict__ counts_priv,
                                float* __restrict__ out)
{
  int j = threadIdx.x;            // 0..1023  (g*16 + col)
  int g = j >> 4;
  float s = 0.f, c = 0.f;
  for (int p = 0; p < NPART; ++p) {
    s += sums_priv[p * NGRAPH * 16 + j];
    c += counts_priv[p * NGRAPH + g];
  }
  out[j] = s / fmaxf(c, 1.f);
}

extern "C" void kernel_launch(void* const* d_in, const int* in_sizes, int n_in,
                              void* d_out, int out_size, void* d_ws, size_t ws_size,
                              hipStream_t stream)
{
  const int*   h0  = (const int*)  d_in[0];
  const int*   src = (const int*)  d_in[1];
  const int*   dst = (const int*)  d_in[2];
  const int*   gid = (const int*)  d_in[3];
  const float* emb = (const float*)d_in[4];
  const float* Wfc = (const float*)d_in[5];
  const float* al  = (const float*)d_in[6];
  const float* ar  = (const float*)d_in[7];
  const float* bg  = (const float*)d_in[8];
  const float* W1  = (const float*)d_in[9];
  const float* b1  = (const float*)d_in[10];
  const float* W2  = (const float*)d_in[11];
  const float* b2  = (const float*)d_in[12];
  float* out = (float*)d_out;

  char* ws = (char*)d_ws;
  size_t off = 0;
  auto alloc = [&](size_t bytes) -> void* {
    off = (off + 255) & ~(size_t)255;
    void* p = ws + off;
    off += bytes;
    return p;
  };
  unsigned short* emb_bf  = (unsigned short*)alloc((size_t)VOCAB * HDIM * 2);
  unsigned short* Wt      = (unsigned short*)alloc((size_t)FDIM * HDIM * 2);
  unsigned short* W1t     = (unsigned short*)alloc((size_t)128 * 64 * 2);
  unsigned short* W2t     = (unsigned short*)alloc((size_t)16 * 128 * 2);
  unsigned short* proj_bf = (unsigned short*)alloc((size_t)VOCAB * FDIM * 2);
  unsigned short* h2bf    = (unsigned short*)alloc((size_t)NNODES * 64 * 2);
  uint2*  recs   = (uint2*) alloc((size_t)NEDGES * 8);
  float*  elv    = (float*) alloc((size_t)VOCAB * 3 * 4);
  float*  erv    = (float*) alloc((size_t)VOCAB * 3 * 4);
  float*  nel    = (float*) alloc((size_t)NNODES * 3 * 4);
  float*  ner    = (float*) alloc((size_t)NNODES * 3 * 4);
  int*    cnt    = (int*)   alloc((size_t)NNODES * 4);
  int*    offs   = (int*)   alloc((size_t)(NNODES + 1) * 4);
  int*    cursor = (int*)   alloc((size_t)NNODES * 4);
  int*    bsum   = (int*)   alloc((size_t)128 * 4);
  float*  sums   = (float*) alloc((size_t)NPART * NGRAPH * 16 * 4);
  float*  cnts   = (float*) alloc((size_t)NPART * NGRAPH * 4);

  hipMemsetAsync(cnt,    0, (size_t)NNODES * 4, stream);
  hipMemsetAsync(cursor, 0, (size_t)NNODES * 4, stream);
  hipMemsetAsync(sums,   0, (size_t)NPART * NGRAPH * 16 * 4, stream);
  hipMemsetAsync(cnts,   0, (size_t)NPART * NGRAPH * 4, stream);

  const int NB = (NNODES + 1023) / 1024;   // 98

  conv_emb_kernel<<<(VOCAB * HDIM / 4 + 255) / 256, 256, 0, stream>>>(
      emb, emb_bf, VOCAB * HDIM);
  conv_weights_kernel<<<(HDIM * FDIM + 128 * 64 + 16 * 128 + 255) / 256, 256, 0, stream>>>(
      Wfc, W1, W2, Wt, W1t, W2t);
  proj_gemm_kernel<<<(VOCAB + 63) / 64, 256, 0, stream>>>(emb_bf, Wt, proj_bf, VOCAB);
  vattn_kernel<<<(VOCAB + 3) / 4, 256, 0, stream>>>(proj_bf, al, ar, elv, erv, VOCAB);
  ngather_kernel<<<(NNODES + 255) / 256, 256, 0, stream>>>(h0, elv, erv, nel, ner, NNODES);
  hist_kernel<<<(NEDGES + 255) / 256, 256, 0, stream>>>(dst, cnt, NEDGES);
  scan_sum_kernel<<<NB, 256, 0, stream>>>(cnt, bsum, NNODES);
  scan_bsum_kernel<<<1, 64, 0, stream>>>(bsum, NB);
  scan_write_kernel<<<NB, 256, 0, stream>>>(cnt, bsum, offs, NNODES, NEDGES);
  scatter_kernel<<<(NEDGES + 255) / 256, 256, 0, stream>>>(src, dst, h0, nel, ner, offs,
                                                           cursor, recs, NEDGES);
  aggregate_kernel<<<(NNODES + 3) / 4, 256, 0, stream>>>(recs, offs, proj_bf, bg,
                                                         h2bf, NNODES);
  post_mfma_kernel<<<(NNODES + 63) / 64, 256, 0, stream>>>(h2bf, W1t, b1, W2t, b2, gid,
                                                           sums, cnts, NNODES);
  finalize_kernel<<<1, 1024, 0, stream>>>(sums, cnts, out);
}

// Round 6
// 356.850 us; speedup vs baseline: 4.1162x; 1.1018x over previous
//
#include <hip/hip_runtime.h>
#include <hip/hip_bf16.h>

#define NNODES 100000
#define NEDGES 1600000
#define VOCAB 50000
#define HDIM 256
#define ADIM 64
#define NHEADS 3
#define FDIM 192   // NHEADS*ADIM
#define NGRAPH 64
#define NPART 64

typedef __attribute__((ext_vector_type(8))) short bf16x8;  // 8 bf16 = 4 VGPRs
typedef __attribute__((ext_vector_type(4))) float f32x4;

__device__ __forceinline__ float bf2f(unsigned short u) {
  return __uint_as_float((unsigned int)u << 16);
}
__device__ __forceinline__ unsigned short f2bf(float f) {
  unsigned int u = __float_as_uint(f);
  u += 0x7FFFu + ((u >> 16) & 1u);   // round-nearest-even
  return (unsigned short)(u >> 16);
}

// All weight transposes+casts in one launch:
//   Wt [192][256] = Wfc^T ;  W1t [128][64] = W1^T ;  W2t [16][128] = W2^T
__global__ __launch_bounds__(256) void conv_weights_kernel(
    const float* __restrict__ Wfc, const float* __restrict__ W1,
    const float* __restrict__ W2, unsigned short* __restrict__ Wt,
    unsigned short* __restrict__ W1t, unsigned short* __restrict__ W2t)
{
  int i = blockIdx.x * 256 + threadIdx.x;
  if (i < HDIM * FDIM) {
    int c = i / HDIM, k = i % HDIM;
    Wt[i] = f2bf(Wfc[(size_t)k * FDIM + c]);
  } else if (i < HDIM * FDIM + 128 * 64) {
    int j = i - HDIM * FDIM;
    int c = j / 64, k = j % 64;
    W1t[j] = f2bf(W1[(size_t)k * 128 + c]);
  } else if (i < HDIM * FDIM + 128 * 64 + 16 * 128) {
    int j = i - HDIM * FDIM - 128 * 64;
    int c = j / 128, k = j % 128;
    W2t[j] = f2bf(W2[(size_t)k * 16 + c]);
  }
}

// ---- proj = emb @ Wfc (bf16 MFMA, f32 A converted inline) + fused attn dots -
// block = 4 waves; wave: 16 rows x 192 cols; K=256 in 8 steps of 32
__global__ __launch_bounds__(256) void proj_gemm_kernel(
    const float* __restrict__ emb,              // [V][256] f32
    const unsigned short* __restrict__ Wt,      // [192][256] bf16
    const float* __restrict__ attn_l,           // [3][64] = [192]
    const float* __restrict__ attn_r,
    unsigned short* __restrict__ proj_bf,       // [V][192]
    float4* __restrict__ elv4, float4* __restrict__ erv4, int V)
{
  const int wave = threadIdx.x >> 6;
  const int lane = threadIdx.x & 63;
  const int row0 = blockIdx.x * 64 + wave * 16;
  const int cb = lane & 15;
  const int q  = lane >> 4;
  int arow = row0 + cb;
  if (arow >= V) arow = V - 1;                  // clamp loads; stores guarded
  const int kgrp = q * 8;

  f32x4 acc[12];
#pragma unroll
  for (int c = 0; c < 12; ++c) acc[c] = (f32x4){0.f, 0.f, 0.f, 0.f};

  const float* arow_p = &emb[(size_t)arow * HDIM + kgrp];
  const unsigned short* bcol_p = &Wt[(size_t)cb * HDIM + kgrp];

#pragma unroll
  for (int ks = 0; ks < 8; ++ks) {
    float4 f0 = *reinterpret_cast<const float4*>(arow_p + ks * 32);
    float4 f1 = *reinterpret_cast<const float4*>(arow_p + ks * 32 + 4);
    bf16x8 a;
    a[0] = (short)f2bf(f0.x); a[1] = (short)f2bf(f0.y);
    a[2] = (short)f2bf(f0.z); a[3] = (short)f2bf(f0.w);
    a[4] = (short)f2bf(f1.x); a[5] = (short)f2bf(f1.y);
    a[6] = (short)f2bf(f1.z); a[7] = (short)f2bf(f1.w);
#pragma unroll
    for (int c = 0; c < 12; ++c) {
      bf16x8 b = *reinterpret_cast<const bf16x8*>(bcol_p + (size_t)c * 16 * HDIM + ks * 32);
      acc[c] = __builtin_amdgcn_mfma_f32_16x16x32_bf16(a, b, acc[c], 0, 0, 0);
    }
  }

  // C/D layout: col = c*16 + cb, row = row0 + 4*q + i
  const int rb = row0 + 4 * q;
#pragma unroll
  for (int i = 0; i < 4; ++i) {
    int r = rb + i;
    if (r < V) {
#pragma unroll
      for (int c = 0; c < 12; ++c)
        proj_bf[(size_t)r * FDIM + c * 16 + cb] = f2bf(acc[c][i]);
    }
  }

  // fused attention dots: el[r] = sum_col feat[r][col]*attn_l[col] (per head)
  float al_v[12], ar_v[12];
#pragma unroll
  for (int c = 0; c < 12; ++c) {
    al_v[c] = attn_l[c * 16 + cb];
    ar_v[c] = attn_r[c * 16 + cb];
  }
  float elp[4][3], erp[4][3];
#pragma unroll
  for (int i = 0; i < 4; ++i)
#pragma unroll
    for (int h = 0; h < 3; ++h) {
      float sl = 0.f, sr = 0.f;
#pragma unroll
      for (int cc = 0; cc < 4; ++cc) {
        float v = acc[h * 4 + cc][i];
        sl += v * al_v[h * 4 + cc];
        sr += v * ar_v[h * 4 + cc];
      }
      elp[i][h] = sl; erp[i][h] = sr;
    }
  // reduce across the 16-lane col group (xor 1,2,4,8 stays inside group)
#pragma unroll
  for (int s = 8; s > 0; s >>= 1) {
#pragma unroll
    for (int i = 0; i < 4; ++i)
#pragma unroll
      for (int h = 0; h < 3; ++h) {
        elp[i][h] += __shfl_xor(elp[i][h], s, 64);
        erp[i][h] += __shfl_xor(erp[i][h], s, 64);
      }
  }
  if (cb == 0) {
#pragma unroll
    for (int i = 0; i < 4; ++i) {
      int r = rb + i;
      if (r < V) {
        elv4[r] = make_float4(elp[i][0], elp[i][1], elp[i][2], 0.f);
        erv4[r] = make_float4(erp[i][0], erp[i][1], erp[i][2], 0.f);
      }
    }
  }
}

// ---------------- hist + rank: rank[e] = old count of dst -------------------
__global__ __launch_bounds__(256) void hist_kernel(
    const int* __restrict__ dst, int* __restrict__ cnt,
    unsigned short* __restrict__ rank16, int E)
{
  int e = blockIdx.x * 256 + threadIdx.x;
  if (e < E) rank16[e] = (unsigned short)atomicAdd(&cnt[dst[e]], 1);
}

__global__ __launch_bounds__(256) void scan_sum_kernel(
    const int* __restrict__ cnt, int* __restrict__ bsum, int n)
{
  __shared__ int red[256];
  int t = threadIdx.x;
  int base = blockIdx.x * 1024 + t * 4;
  int s = 0;
#pragma unroll
  for (int j = 0; j < 4; ++j) if (base + j < n) s += cnt[base + j];
  red[t] = s;
  __syncthreads();
  for (int o = 128; o > 0; o >>= 1) {
    if (t < o) red[t] += red[t + o];
    __syncthreads();
  }
  if (t == 0) bsum[blockIdx.x] = red[0];
}

__global__ void scan_bsum_kernel(int* bsum, int nb)
{
  if (threadIdx.x == 0 && blockIdx.x == 0) {
    int acc = 0;
    for (int i = 0; i < nb; ++i) { int v = bsum[i]; bsum[i] = acc; acc += v; }
  }
}

__global__ __launch_bounds__(256) void scan_write_kernel(
    const int* __restrict__ cnt, const int* __restrict__ bsum,
    int* __restrict__ offs, int n, int total)
{
  __shared__ int sd[256];
  int t = threadIdx.x;
  int base = blockIdx.x * 1024 + t * 4;
  int c[4];
  int ts = 0;
#pragma unroll
  for (int j = 0; j < 4; ++j) { c[j] = (base + j < n) ? cnt[base + j] : 0; ts += c[j]; }
  sd[t] = ts;
  __syncthreads();
  for (int o = 1; o < 256; o <<= 1) {
    int v = (t >= o) ? sd[t - o] : 0;
    __syncthreads();
    sd[t] += v;
    __syncthreads();
  }
  int run = sd[t] - ts + bsum[blockIdx.x];
#pragma unroll
  for (int j = 0; j < 4; ++j) {
    if (base + j < n) offs[base + j] = run;
    run += c[j];
  }
  if (blockIdx.x == 0 && t == 0) offs[n] = total;
}

// ---------------- scatter: recs16[offs[d]+rank[e]] = vocab(src), no atomics -
__global__ __launch_bounds__(256) void scatter_kernel(
    const int* __restrict__ src, const int* __restrict__ dst,
    const int* __restrict__ h0, const unsigned short* __restrict__ rank16,
    const int* __restrict__ offs, unsigned short* __restrict__ recs16, int E)
{
  int e = blockIdx.x * 256 + threadIdx.x;
  if (e >= E) return;
  int p = offs[dst[e]] + (int)rank16[e];
  recs16[p] = (unsigned short)h0[src[e]];
}

// ---------------- per-node aggregation: w computed in-kernel ---------------
__global__ __launch_bounds__(256) void aggregate_kernel(
    const unsigned short* __restrict__ recs16, const int* __restrict__ offs,
    const int* __restrict__ h0,
    const unsigned short* __restrict__ proj_bf,
    const float4* __restrict__ elv4, const float4* __restrict__ erv4,
    const float* __restrict__ bias_gat,
    unsigned short* __restrict__ h2bf, int N)
{
  int lane = threadIdx.x & 63;
  int n = blockIdx.x * 4 + (threadIdx.x >> 6);
  if (n >= N) return;
  const float4 ero = erv4[h0[n]];
  int lo = offs[n], hi = offs[n + 1];
  float a0 = 0.f, a1 = 0.f, a2 = 0.f, d0 = 0.f, d1 = 0.f, d2 = 0.f;

  int i = lo;
  for (; i + 4 <= hi; i += 4) {
    int vs[4];
#pragma unroll
    for (int j = 0; j < 4; ++j) vs[j] = recs16[i + j];
    float4 ev[4];
#pragma unroll
    for (int j = 0; j < 4; ++j) ev[j] = elv4[vs[j]];
    const unsigned short* ps[4];
#pragma unroll
    for (int j = 0; j < 4; ++j) ps[j] = &proj_bf[(size_t)vs[j] * FDIM];
    float g0[4], g1[4], g2[4];
#pragma unroll
    for (int j = 0; j < 4; ++j) {       // 12 independent gathers in flight
      g0[j] = bf2f(ps[j][lane]);
      g1[j] = bf2f(ps[j][64 + lane]);
      g2[j] = bf2f(ps[j][128 + lane]);
    }
#pragma unroll
    for (int j = 0; j < 4; ++j) {
      float e0 = ev[j].x + ero.x, e1 = ev[j].y + ero.y, e2 = ev[j].z + ero.z;
      e0 = e0 > 0.f ? e0 : 0.2f * e0;   // leaky_relu 0.2
      e1 = e1 > 0.f ? e1 : 0.2f * e1;
      e2 = e2 > 0.f ? e2 : 0.2f * e2;
      float w0 = __expf(e0), w1 = __expf(e1), w2 = __expf(e2);
      a0 += w0 * g0[j]; a1 += w1 * g1[j]; a2 += w2 * g2[j];
      d0 += w0; d1 += w1; d2 += w2;
    }
  }
  for (; i < hi; ++i) {
    int vs = recs16[i];
    float4 ev = elv4[vs];
    const unsigned short* ps = &proj_bf[(size_t)vs * FDIM];
    float e0 = ev.x + ero.x, e1 = ev.y + ero.y, e2 = ev.z + ero.z;
    e0 = e0 > 0.f ? e0 : 0.2f * e0;
    e1 = e1 > 0.f ? e1 : 0.2f * e1;
    e2 = e2 > 0.f ? e2 : 0.2f * e2;
    float w0 = __expf(e0), w1 = __expf(e1), w2 = __expf(e2);
    a0 += w0 * bf2f(ps[lane]);
    a1 += w1 * bf2f(ps[64 + lane]);
    a2 += w2 * bf2f(ps[128 + lane]);
    d0 += w0; d1 += w1; d2 += w2;
  }

  float i0 = d0 > 0.f ? 1.f / d0 : 0.f;   // guard 0-in-degree
  float i1 = d1 > 0.f ? 1.f / d1 : 0.f;
  float i2 = d2 > 0.f ? 1.f / d2 : 0.f;
  float r0 = a0 * i0 + bias_gat[lane];
  float r1 = a1 * i1 + bias_gat[64 + lane];
  float r2 = a2 * i2 + bias_gat[128 + lane];
  float h2 = (fmaxf(r0, 0.f) + fmaxf(r1, 0.f) + fmaxf(r2, 0.f)) * (1.f / 3.f);
  h2bf[(size_t)n * 64 + lane] = f2bf(h2);
}

// ---------------- MLP via MFMA: relu(h2@W1+b1)@W2+b2 + graph atomics --------
__global__ __launch_bounds__(256) void post_mfma_kernel(
    const unsigned short* __restrict__ h2bf,   // [N][64]
    const unsigned short* __restrict__ W1t,    // [128][64]
    const float* __restrict__ b1,
    const unsigned short* __restrict__ W2t,    // [16][128]
    const float* __restrict__ b2, const int* __restrict__ gid,
    float* __restrict__ sums_priv, float* __restrict__ counts_priv, int N)
{
  __shared__ unsigned short z_lds[64 * 128];
  const int wave = threadIdx.x >> 6;
  const int lane = threadIdx.x & 63;
  const int r = lane & 15;
  const int q = lane >> 4;
  const int kg = q * 8;
  const int rw0 = blockIdx.x * 64 + wave * 16;

  int arow = rw0 + r;
  if (arow >= N) arow = N - 1;       // clamp loads; stores guarded

  f32x4 acc1[8];
#pragma unroll
  for (int c = 0; c < 8; ++c) acc1[c] = (f32x4){0.f, 0.f, 0.f, 0.f};

#pragma unroll
  for (int ks = 0; ks < 2; ++ks) {
    bf16x8 a = *reinterpret_cast<const bf16x8*>(&h2bf[(size_t)arow * 64 + kg + ks * 32]);
#pragma unroll
    for (int c = 0; c < 8; ++c) {
      bf16x8 b = *reinterpret_cast<const bf16x8*>(&W1t[(size_t)(c * 16 + r) * 64 + kg + ks * 32]);
      acc1[c] = __builtin_amdgcn_mfma_f32_16x16x32_bf16(a, b, acc1[c], 0, 0, 0);
    }
  }
#pragma unroll
  for (int c = 0; c < 8; ++c) {
    float bb = b1[c * 16 + r];
#pragma unroll
    for (int i = 0; i < 4; ++i) {
      float z = acc1[c][i] + bb;
      z = z > 0.f ? z : 0.f;
      z_lds[(wave * 16 + 4 * q + i) * 128 + c * 16 + r] = f2bf(z);
    }
  }
  __syncthreads();

  f32x4 acc2 = (f32x4){0.f, 0.f, 0.f, 0.f};
#pragma unroll
  for (int ks = 0; ks < 4; ++ks) {
    bf16x8 a = *reinterpret_cast<const bf16x8*>(&z_lds[(wave * 16 + r) * 128 + kg + ks * 32]);
    bf16x8 b = *reinterpret_cast<const bf16x8*>(&W2t[(size_t)r * 128 + kg + ks * 32]);
    acc2 = __builtin_amdgcn_mfma_f32_16x16x32_bf16(a, b, acc2, 0, 0, 0);
  }
  const int part = blockIdx.x & (NPART - 1);
  float bb2 = b2[r];
#pragma unroll
  for (int i = 0; i < 4; ++i) {
    int row = rw0 + 4 * q + i;
    if (row < N) {
      int g = gid[row];
      atomicAdd(&sums_priv[(part * NGRAPH + g) * 16 + r], acc2[i] + bb2);
      if (r == 0) atomicAdd(&counts_priv[part * NGRAPH + g], 1.f);
    }
  }
}

// ---------------- reduce privatized graph sums -> output --------------------
__global__ void finalize_kernel(const float* __restrict__ sums_priv,
                                const float* __restrict__ counts_priv,
                                float* __restrict__ out)
{
  int j = threadIdx.x;            // 0..1023  (g*16 + col)
  int g = j >> 4;
  float s = 0.f, c = 0.f;
  for (int p = 0; p < NPART; ++p) {
    s += sums_priv[p * NGRAPH * 16 + j];
    c += counts_priv[p * NGRAPH + g];
  }
  out[j] = s / fmaxf(c, 1.f);
}

extern "C" void kernel_launch(void* const* d_in, const int* in_sizes, int n_in,
                              void* d_out, int out_size, void* d_ws, size_t ws_size,
                              hipStream_t stream)
{
  const int*   h0  = (const int*)  d_in[0];
  const int*   src = (const int*)  d_in[1];
  const int*   dst = (const int*)  d_in[2];
  const int*   gid = (const int*)  d_in[3];
  const float* emb = (const float*)d_in[4];
  const float* Wfc = (const float*)d_in[5];
  const float* al  = (const float*)d_in[6];
  const float* ar  = (const float*)d_in[7];
  const float* bg  = (const float*)d_in[8];
  const float* W1  = (const float*)d_in[9];
  const float* b1  = (const float*)d_in[10];
  const float* W2  = (const float*)d_in[11];
  const float* b2  = (const float*)d_in[12];
  float* out = (float*)d_out;

  char* ws = (char*)d_ws;
  size_t off = 0;
  auto alloc = [&](size_t bytes) -> void* {
    off = (off + 255) & ~(size_t)255;
    void* p = ws + off;
    off += bytes;
    return p;
  };
  unsigned short* Wt      = (unsigned short*)alloc((size_t)FDIM * HDIM * 2);
  unsigned short* W1t     = (unsigned short*)alloc((size_t)128 * 64 * 2);
  unsigned short* W2t     = (unsigned short*)alloc((size_t)16 * 128 * 2);
  unsigned short* proj_bf = (unsigned short*)alloc((size_t)VOCAB * FDIM * 2);
  unsigned short* h2bf    = (unsigned short*)alloc((size_t)NNODES * 64 * 2);
  unsigned short* recs16  = (unsigned short*)alloc((size_t)NEDGES * 2);
  unsigned short* rank16  = (unsigned short*)alloc((size_t)NEDGES * 2);
  float4* elv4   = (float4*)alloc((size_t)VOCAB * 16);
  float4* erv4   = (float4*)alloc((size_t)VOCAB * 16);
  int*    cnt    = (int*)   alloc((size_t)NNODES * 4);
  int*    offs   = (int*)   alloc((size_t)(NNODES + 1) * 4);
  int*    bsum   = (int*)   alloc((size_t)128 * 4);
  float*  sums   = (float*) alloc((size_t)NPART * NGRAPH * 16 * 4);
  float*  cnts   = (float*) alloc((size_t)NPART * NGRAPH * 4);

  hipMemsetAsync(cnt,  0, (size_t)NNODES * 4, stream);
  hipMemsetAsync(sums, 0, (size_t)NPART * NGRAPH * 16 * 4, stream);
  hipMemsetAsync(cnts, 0, (size_t)NPART * NGRAPH * 4, stream);

  const int NB = (NNODES + 1023) / 1024;   // 98

  conv_weights_kernel<<<(HDIM * FDIM + 128 * 64 + 16 * 128 + 255) / 256, 256, 0, stream>>>(
      Wfc, W1, W2, Wt, W1t, W2t);
  proj_gemm_kernel<<<(VOCAB + 63) / 64, 256, 0, stream>>>(emb, Wt, al, ar,
                                                          proj_bf, elv4, erv4, VOCAB);
  hist_kernel<<<(NEDGES + 255) / 256, 256, 0, stream>>>(dst, cnt, rank16, NEDGES);
  scan_sum_kernel<<<NB, 256, 0, stream>>>(cnt, bsum, NNODES);
  scan_bsum_kernel<<<1, 64, 0, stream>>>(bsum, NB);
  scan_write_kernel<<<NB, 256, 0, stream>>>(cnt, bsum, offs, NNODES, NEDGES);
  scatter_kernel<<<(NEDGES + 255) / 256, 256, 0, stream>>>(src, dst, h0, rank16, offs,
                                                           recs16, NEDGES);
  aggregate_kernel<<<(NNODES + 3) / 4, 256, 0, stream>>>(recs16, offs, h0, proj_bf,
                                                         elv4, erv4, bg, h2bf, NNODES);
  post_mfma_kernel<<<(NNODES + 63) / 64, 256, 0, stream>>>(h2bf, W1t, b1, W2t, b2, gid,
                                                           sums, cnts, NNODES);
  finalize_kernel<<<1, 1024, 0, stream>>>(sums, cnts, out);
}

// Round 7
// 346.875 us; speedup vs baseline: 4.2345x; 1.0288x over previous
//
#include <hip/hip_runtime.h>
#include <hip/hip_bf16.h>

#define NNODES 100000
#define NEDGES 1600000
#define VOCAB 50000
#define HDIM 256
#define ADIM 64
#define NHEADS 3
#define FDIM 192   // NHEADS*ADIM
#define NGRAPH 64
#define NPART 64

typedef __attribute__((ext_vector_type(8))) short bf16x8;  // 8 bf16 = 4 VGPRs
typedef __attribute__((ext_vector_type(4))) float f32x4;

__device__ __forceinline__ float bf2f(unsigned short u) {
  return __uint_as_float((unsigned int)u << 16);
}
__device__ __forceinline__ unsigned short f2bf(float f) {
  unsigned int u = __float_as_uint(f);
  u += 0x7FFFu + ((u >> 16) & 1u);   // round-nearest-even
  return (unsigned short)(u >> 16);
}

// All weight transposes+casts in one launch:
//   Wt [192][256] = Wfc^T ;  W1t [128][64] = W1^T ;  W2t [16][128] = W2^T
__global__ __launch_bounds__(256) void conv_weights_kernel(
    const float* __restrict__ Wfc, const float* __restrict__ W1,
    const float* __restrict__ W2, unsigned short* __restrict__ Wt,
    unsigned short* __restrict__ W1t, unsigned short* __restrict__ W2t)
{
  int i = blockIdx.x * 256 + threadIdx.x;
  if (i < HDIM * FDIM) {
    int c = i / HDIM, k = i % HDIM;
    Wt[i] = f2bf(Wfc[(size_t)k * FDIM + c]);
  } else if (i < HDIM * FDIM + 128 * 64) {
    int j = i - HDIM * FDIM;
    int c = j / 64, k = j % 64;
    W1t[j] = f2bf(W1[(size_t)k * 128 + c]);
  } else if (i < HDIM * FDIM + 128 * 64 + 16 * 128) {
    int j = i - HDIM * FDIM - 128 * 64;
    int c = j / 128, k = j % 128;
    W2t[j] = f2bf(W2[(size_t)k * 16 + c]);
  }
}

// ---- proj = emb @ Wfc (bf16 MFMA, f32 A converted inline) + fused attn dots -
__global__ __launch_bounds__(256) void proj_gemm_kernel(
    const float* __restrict__ emb,              // [V][256] f32
    const unsigned short* __restrict__ Wt,      // [192][256] bf16
    const float* __restrict__ attn_l,           // [3][64] = [192]
    const float* __restrict__ attn_r,
    unsigned short* __restrict__ proj_bf,       // [V][192]
    float4* __restrict__ elv4, float4* __restrict__ erv4, int V)
{
  const int wave = threadIdx.x >> 6;
  const int lane = threadIdx.x & 63;
  const int row0 = blockIdx.x * 64 + wave * 16;
  const int cb = lane & 15;
  const int q  = lane >> 4;
  int arow = row0 + cb;
  if (arow >= V) arow = V - 1;                  // clamp loads; stores guarded
  const int kgrp = q * 8;

  f32x4 acc[12];
#pragma unroll
  for (int c = 0; c < 12; ++c) acc[c] = (f32x4){0.f, 0.f, 0.f, 0.f};

  const float* arow_p = &emb[(size_t)arow * HDIM + kgrp];
  const unsigned short* bcol_p = &Wt[(size_t)cb * HDIM + kgrp];

#pragma unroll
  for (int ks = 0; ks < 8; ++ks) {
    float4 f0 = *reinterpret_cast<const float4*>(arow_p + ks * 32);
    float4 f1 = *reinterpret_cast<const float4*>(arow_p + ks * 32 + 4);
    bf16x8 a;
    a[0] = (short)f2bf(f0.x); a[1] = (short)f2bf(f0.y);
    a[2] = (short)f2bf(f0.z); a[3] = (short)f2bf(f0.w);
    a[4] = (short)f2bf(f1.x); a[5] = (short)f2bf(f1.y);
    a[6] = (short)f2bf(f1.z); a[7] = (short)f2bf(f1.w);
#pragma unroll
    for (int c = 0; c < 12; ++c) {
      bf16x8 b = *reinterpret_cast<const bf16x8*>(bcol_p + (size_t)c * 16 * HDIM + ks * 32);
      acc[c] = __builtin_amdgcn_mfma_f32_16x16x32_bf16(a, b, acc[c], 0, 0, 0);
    }
  }

  const int rb = row0 + 4 * q;
#pragma unroll
  for (int i = 0; i < 4; ++i) {
    int r = rb + i;
    if (r < V) {
#pragma unroll
      for (int c = 0; c < 12; ++c)
        proj_bf[(size_t)r * FDIM + c * 16 + cb] = f2bf(acc[c][i]);
    }
  }

  // fused attention dots
  float al_v[12], ar_v[12];
#pragma unroll
  for (int c = 0; c < 12; ++c) {
    al_v[c] = attn_l[c * 16 + cb];
    ar_v[c] = attn_r[c * 16 + cb];
  }
  float elp[4][3], erp[4][3];
#pragma unroll
  for (int i = 0; i < 4; ++i)
#pragma unroll
    for (int h = 0; h < 3; ++h) {
      float sl = 0.f, sr = 0.f;
#pragma unroll
      for (int cc = 0; cc < 4; ++cc) {
        float v = acc[h * 4 + cc][i];
        sl += v * al_v[h * 4 + cc];
        sr += v * ar_v[h * 4 + cc];
      }
      elp[i][h] = sl; erp[i][h] = sr;
    }
#pragma unroll
  for (int s = 8; s > 0; s >>= 1) {
#pragma unroll
    for (int i = 0; i < 4; ++i)
#pragma unroll
      for (int h = 0; h < 3; ++h) {
        elp[i][h] += __shfl_xor(elp[i][h], s, 64);
        erp[i][h] += __shfl_xor(erp[i][h], s, 64);
      }
  }
  if (cb == 0) {
#pragma unroll
    for (int i = 0; i < 4; ++i) {
      int r = rb + i;
      if (r < V) {
        elv4[r] = make_float4(elp[i][0], elp[i][1], elp[i][2], 0.f);
        erv4[r] = make_float4(erp[i][0], erp[i][1], erp[i][2], 0.f);
      }
    }
  }
}

// ---------------- hist + rank: rank[e] = old count of dst -------------------
__global__ __launch_bounds__(256) void hist_kernel(
    const int* __restrict__ dst, int* __restrict__ cnt,
    unsigned short* __restrict__ rank16, int E)
{
  int e = blockIdx.x * 256 + threadIdx.x;
  if (e < E) rank16[e] = (unsigned short)atomicAdd(&cnt[dst[e]], 1);
}

__global__ __launch_bounds__(256) void scan_sum_kernel(
    const int* __restrict__ cnt, int* __restrict__ bsum, int n)
{
  __shared__ int red[256];
  int t = threadIdx.x;
  int base = blockIdx.x * 1024 + t * 4;
  int s = 0;
#pragma unroll
  for (int j = 0; j < 4; ++j) if (base + j < n) s += cnt[base + j];
  red[t] = s;
  __syncthreads();
  for (int o = 128; o > 0; o >>= 1) {
    if (t < o) red[t] += red[t + o];
    __syncthreads();
  }
  if (t == 0) bsum[blockIdx.x] = red[0];
}

__global__ void scan_bsum_kernel(int* bsum, int nb)
{
  if (threadIdx.x == 0 && blockIdx.x == 0) {
    int acc = 0;
    for (int i = 0; i < nb; ++i) { int v = bsum[i]; bsum[i] = acc; acc += v; }
  }
}

__global__ __launch_bounds__(256) void scan_write_kernel(
    const int* __restrict__ cnt, const int* __restrict__ bsum,
    int* __restrict__ offs, int n, int total)
{
  __shared__ int sd[256];
  int t = threadIdx.x;
  int base = blockIdx.x * 1024 + t * 4;
  int c[4];
  int ts = 0;
#pragma unroll
  for (int j = 0; j < 4; ++j) { c[j] = (base + j < n) ? cnt[base + j] : 0; ts += c[j]; }
  sd[t] = ts;
  __syncthreads();
  for (int o = 1; o < 256; o <<= 1) {
    int v = (t >= o) ? sd[t - o] : 0;
    __syncthreads();
    sd[t] += v;
    __syncthreads();
  }
  int run = sd[t] - ts + bsum[blockIdx.x];
#pragma unroll
  for (int j = 0; j < 4; ++j) {
    if (base + j < n) offs[base + j] = run;
    run += c[j];
  }
  if (blockIdx.x == 0 && t == 0) offs[n] = total;
}

// ---------------- scatter: recs16[offs[d]+rank[e]] = vocab(src) -------------
__global__ __launch_bounds__(256) void scatter_kernel(
    const int* __restrict__ src, const int* __restrict__ dst,
    const int* __restrict__ h0, const unsigned short* __restrict__ rank16,
    const int* __restrict__ offs, unsigned short* __restrict__ recs16, int E)
{
  int e = blockIdx.x * 256 + threadIdx.x;
  if (e >= E) return;
  int p = offs[dst[e]] + (int)rank16[e];
  recs16[p] = (unsigned short)h0[src[e]];
}

// ---------------- per-node weights: w = exp(leaky(el+er)) once per EDGE -----
// thread per node; coalesced-ish 8B writes in sorted order; inv-denominator out
__global__ __launch_bounds__(256) void wexp_kernel(
    const unsigned short* __restrict__ recs16, const int* __restrict__ offs,
    const int* __restrict__ h0,
    const float4* __restrict__ elv4, const float4* __restrict__ erv4,
    uint2* __restrict__ wrec, float4* __restrict__ inv4, int N)
{
  int n = blockIdx.x * 256 + threadIdx.x;
  if (n >= N) return;
  const float4 ero = erv4[h0[n]];
  int lo = offs[n], hi = offs[n + 1];
  float d0 = 0.f, d1 = 0.f, d2 = 0.f;
  for (int p = lo; p < hi; ++p) {
    unsigned v = recs16[p];
    float4 ev = elv4[v];
    float e0 = ev.x + ero.x, e1 = ev.y + ero.y, e2 = ev.z + ero.z;
    e0 = e0 > 0.f ? e0 : 0.2f * e0;   // leaky_relu 0.2
    e1 = e1 > 0.f ? e1 : 0.2f * e1;
    e2 = e2 > 0.f ? e2 : 0.2f * e2;
    unsigned short u0 = f2bf(__expf(e0));
    unsigned short u1 = f2bf(__expf(e1));
    unsigned short u2 = f2bf(__expf(e2));
    d0 += bf2f(u0); d1 += bf2f(u1); d2 += bf2f(u2);   // sum ROUNDED w
    wrec[p] = make_uint2(v | ((unsigned)u0 << 16),
                         (unsigned)u1 | ((unsigned)u2 << 16));
  }
  inv4[n] = make_float4(d0 > 0.f ? 1.f / d0 : 0.f,
                        d1 > 0.f ? 1.f / d1 : 0.f,
                        d2 > 0.f ? 1.f / d2 : 0.f, 0.f);
}

// ---------------- per-node aggregation: pure gather+FMA ---------------------
__global__ __launch_bounds__(256) void aggregate_kernel(
    const uint2* __restrict__ wrec, const int* __restrict__ offs,
    const float4* __restrict__ inv4,
    const unsigned short* __restrict__ proj_bf, const float* __restrict__ bias_gat,
    unsigned short* __restrict__ h2bf, int N)
{
  int lane = threadIdx.x & 63;
  int n = blockIdx.x * 4 + (threadIdx.x >> 6);
  if (n >= N) return;
  int lo = offs[n], hi = offs[n + 1];
  float a0 = 0.f, a1 = 0.f, a2 = 0.f;

  int i = lo;
  for (; i + 4 <= hi; i += 4) {
    uint2 r[4];
#pragma unroll
    for (int j = 0; j < 4; ++j) r[j] = wrec[i + j];
    const unsigned short* ps[4];
#pragma unroll
    for (int j = 0; j < 4; ++j)
      ps[j] = &proj_bf[(size_t)(r[j].x & 0xFFFFu) * FDIM];
    float g0[4], g1[4], g2[4];
#pragma unroll
    for (int j = 0; j < 4; ++j) {       // 12 independent gathers in flight
      g0[j] = bf2f(ps[j][lane]);
      g1[j] = bf2f(ps[j][64 + lane]);
      g2[j] = bf2f(ps[j][128 + lane]);
    }
#pragma unroll
    for (int j = 0; j < 4; ++j) {
      a0 += bf2f((unsigned short)(r[j].x >> 16)) * g0[j];
      a1 += bf2f((unsigned short)(r[j].y & 0xFFFFu)) * g1[j];
      a2 += bf2f((unsigned short)(r[j].y >> 16)) * g2[j];
    }
  }
  for (; i < hi; ++i) {
    uint2 r = wrec[i];
    const unsigned short* ps = &proj_bf[(size_t)(r.x & 0xFFFFu) * FDIM];
    a0 += bf2f((unsigned short)(r.x >> 16)) * bf2f(ps[lane]);
    a1 += bf2f((unsigned short)(r.y & 0xFFFFu)) * bf2f(ps[64 + lane]);
    a2 += bf2f((unsigned short)(r.y >> 16)) * bf2f(ps[128 + lane]);
  }

  const float4 inv = inv4[n];
  float r0 = a0 * inv.x + bias_gat[lane];
  float r1 = a1 * inv.y + bias_gat[64 + lane];
  float r2 = a2 * inv.z + bias_gat[128 + lane];
  float h2 = (fmaxf(r0, 0.f) + fmaxf(r1, 0.f) + fmaxf(r2, 0.f)) * (1.f / 3.f);
  h2bf[(size_t)n * 64 + lane] = f2bf(h2);
}

// ---------------- MLP via MFMA: relu(h2@W1+b1)@W2+b2 + graph atomics --------
__global__ __launch_bounds__(256) void post_mfma_kernel(
    const unsigned short* __restrict__ h2bf,   // [N][64]
    const unsigned short* __restrict__ W1t,    // [128][64]
    const float* __restrict__ b1,
    const unsigned short* __restrict__ W2t,    // [16][128]
    const float* __restrict__ b2, const int* __restrict__ gid,
    float* __restrict__ sums_priv, float* __restrict__ counts_priv, int N)
{
  __shared__ unsigned short z_lds[64 * 128];
  const int wave = threadIdx.x >> 6;
  const int lane = threadIdx.x & 63;
  const int r = lane & 15;
  const int q = lane >> 4;
  const int kg = q * 8;
  const int rw0 = blockIdx.x * 64 + wave * 16;

  int arow = rw0 + r;
  if (arow >= N) arow = N - 1;       // clamp loads; stores guarded

  f32x4 acc1[8];
#pragma unroll
  for (int c = 0; c < 8; ++c) acc1[c] = (f32x4){0.f, 0.f, 0.f, 0.f};

#pragma unroll
  for (int ks = 0; ks < 2; ++ks) {
    bf16x8 a = *reinterpret_cast<const bf16x8*>(&h2bf[(size_t)arow * 64 + kg + ks * 32]);
#pragma unroll
    for (int c = 0; c < 8; ++c) {
      bf16x8 b = *reinterpret_cast<const bf16x8*>(&W1t[(size_t)(c * 16 + r) * 64 + kg + ks * 32]);
      acc1[c] = __builtin_amdgcn_mfma_f32_16x16x32_bf16(a, b, acc1[c], 0, 0, 0);
    }
  }
#pragma unroll
  for (int c = 0; c < 8; ++c) {
    float bb = b1[c * 16 + r];
#pragma unroll
    for (int i = 0; i < 4; ++i) {
      float z = acc1[c][i] + bb;
      z = z > 0.f ? z : 0.f;
      z_lds[(wave * 16 + 4 * q + i) * 128 + c * 16 + r] = f2bf(z);
    }
  }
  __syncthreads();

  f32x4 acc2 = (f32x4){0.f, 0.f, 0.f, 0.f};
#pragma unroll
  for (int ks = 0; ks < 4; ++ks) {
    bf16x8 a = *reinterpret_cast<const bf16x8*>(&z_lds[(wave * 16 + r) * 128 + kg + ks * 32]);
    bf16x8 b = *reinterpret_cast<const bf16x8*>(&W2t[(size_t)r * 128 + kg + ks * 32]);
    acc2 = __builtin_amdgcn_mfma_f32_16x16x32_bf16(a, b, acc2, 0, 0, 0);
  }
  const int part = blockIdx.x & (NPART - 1);
  float bb2 = b2[r];
#pragma unroll
  for (int i = 0; i < 4; ++i) {
    int row = rw0 + 4 * q + i;
    if (row < N) {
      int g = gid[row];
      atomicAdd(&sums_priv[(part * NGRAPH + g) * 16 + r], acc2[i] + bb2);
      if (r == 0) atomicAdd(&counts_priv[part * NGRAPH + g], 1.f);
    }
  }
}

// ---------------- reduce privatized graph sums -> output --------------------
__global__ void finalize_kernel(const float* __restrict__ sums_priv,
                                const float* __restrict__ counts_priv,
                                float* __restrict__ out)
{
  int j = threadIdx.x;            // 0..1023  (g*16 + col)
  int g = j >> 4;
  float s = 0.f, c = 0.f;
  for (int p = 0; p < NPART; ++p) {
    s += sums_priv[p * NGRAPH * 16 + j];
    c += counts_priv[p * NGRAPH + g];
  }
  out[j] = s / fmaxf(c, 1.f);
}

extern "C" void kernel_launch(void* const* d_in, const int* in_sizes, int n_in,
                              void* d_out, int out_size, void* d_ws, size_t ws_size,
                              hipStream_t stream)
{
  const int*   h0  = (const int*)  d_in[0];
  const int*   src = (const int*)  d_in[1];
  const int*   dst = (const int*)  d_in[2];
  const int*   gid = (const int*)  d_in[3];
  const float* emb = (const float*)d_in[4];
  const float* Wfc = (const float*)d_in[5];
  const float* al  = (const float*)d_in[6];
  const float* ar  = (const float*)d_in[7];
  const float* bg  = (const float*)d_in[8];
  const float* W1  = (const float*)d_in[9];
  const float* b1  = (const float*)d_in[10];
  const float* W2  = (const float*)d_in[11];
  const float* b2  = (const float*)d_in[12];
  float* out = (float*)d_out;

  char* ws = (char*)d_ws;
  size_t off = 0;
  auto alloc = [&](size_t bytes) -> void* {
    off = (off + 255) & ~(size_t)255;
    void* p = ws + off;
    off += bytes;
    return p;
  };
  unsigned short* Wt      = (unsigned short*)alloc((size_t)FDIM * HDIM * 2);
  unsigned short* W1t     = (unsigned short*)alloc((size_t)128 * 64 * 2);
  unsigned short* W2t     = (unsigned short*)alloc((size_t)16 * 128 * 2);
  unsigned short* proj_bf = (unsigned short*)alloc((size_t)VOCAB * FDIM * 2);
  unsigned short* h2bf    = (unsigned short*)alloc((size_t)NNODES * 64 * 2);
  unsigned short* recs16  = (unsigned short*)alloc((size_t)NEDGES * 2);
  unsigned short* rank16  = (unsigned short*)alloc((size_t)NEDGES * 2);
  uint2*  wrec   = (uint2*) alloc((size_t)NEDGES * 8);
  float4* elv4   = (float4*)alloc((size_t)VOCAB * 16);
  float4* erv4   = (float4*)alloc((size_t)VOCAB * 16);
  float4* inv4   = (float4*)alloc((size_t)NNODES * 16);
  int*    cnt    = (int*)   alloc((size_t)NNODES * 4);
  int*    offs   = (int*)   alloc((size_t)(NNODES + 1) * 4);
  int*    bsum   = (int*)   alloc((size_t)128 * 4);
  float*  sums   = (float*) alloc((size_t)NPART * NGRAPH * 16 * 4);
  float*  cnts   = (float*) alloc((size_t)NPART * NGRAPH * 4);

  hipMemsetAsync(cnt,  0, (size_t)NNODES * 4, stream);
  hipMemsetAsync(sums, 0, (size_t)NPART * NGRAPH * 16 * 4, stream);
  hipMemsetAsync(cnts, 0, (size_t)NPART * NGRAPH * 4, stream);

  const int NB = (NNODES + 1023) / 1024;   // 98

  conv_weights_kernel<<<(HDIM * FDIM + 128 * 64 + 16 * 128 + 255) / 256, 256, 0, stream>>>(
      Wfc, W1, W2, Wt, W1t, W2t);
  proj_gemm_kernel<<<(VOCAB + 63) / 64, 256, 0, stream>>>(emb, Wt, al, ar,
                                                          proj_bf, elv4, erv4, VOCAB);
  hist_kernel<<<(NEDGES + 255) / 256, 256, 0, stream>>>(dst, cnt, rank16, NEDGES);
  scan_sum_kernel<<<NB, 256, 0, stream>>>(cnt, bsum, NNODES);
  scan_bsum_kernel<<<1, 64, 0, stream>>>(bsum, NB);
  scan_write_kernel<<<NB, 256, 0, stream>>>(cnt, bsum, offs, NNODES, NEDGES);
  scatter_kernel<<<(NEDGES + 255) / 256, 256, 0, stream>>>(src, dst, h0, rank16, offs,
                                                           recs16, NEDGES);
  wexp_kernel<<<(NNODES + 255) / 256, 256, 0, stream>>>(recs16, offs, h0, elv4, erv4,
                                                        wrec, inv4, NNODES);
  aggregate_kernel<<<(NNODES + 3) / 4, 256, 0, stream>>>(wrec, offs, inv4, proj_bf,
                                                         bg, h2bf, NNODES);
  post_mfma_kernel<<<(NNODES + 63) / 64, 256, 0, stream>>>(h2bf, W1t, b1, W2t, b2, gid,
                                                           sums, cnts, NNODES);
  finalize_kernel<<<1, 1024, 0, stream>>>(sums, cnts, out);
}

// Round 8
// 346.095 us; speedup vs baseline: 4.2441x; 1.0023x over previous
//
#include <hip/hip_runtime.h>
#include <hip/hip_bf16.h>

#define NNODES 100000
#define NEDGES 1600000
#define VOCAB 50000
#define HDIM 256
#define ADIM 64
#define NHEADS 3
#define FDIM 192   // NHEADS*ADIM
#define NGRAPH 64
#define NPART 64

typedef __attribute__((ext_vector_type(8))) short bf16x8;  // 8 bf16 = 4 VGPRs
typedef __attribute__((ext_vector_type(4))) float f32x4;

__device__ __forceinline__ float bf2f(unsigned short u) {
  return __uint_as_float((unsigned int)u << 16);
}
__device__ __forceinline__ unsigned short f2bf(float f) {
  unsigned int u = __float_as_uint(f);
  u += 0x7FFFu + ((u >> 16) & 1u);   // round-nearest-even
  return (unsigned short)(u >> 16);
}

// All weight transposes+casts in one launch:
//   Wt [192][256] = Wfc^T ;  W1t [128][64] = W1^T ;  W2t [16][128] = W2^T
__global__ __launch_bounds__(256) void conv_weights_kernel(
    const float* __restrict__ Wfc, const float* __restrict__ W1,
    const float* __restrict__ W2, unsigned short* __restrict__ Wt,
    unsigned short* __restrict__ W1t, unsigned short* __restrict__ W2t)
{
  int i = blockIdx.x * 256 + threadIdx.x;
  if (i < HDIM * FDIM) {
    int c = i / HDIM, k = i % HDIM;
    Wt[i] = f2bf(Wfc[(size_t)k * FDIM + c]);
  } else if (i < HDIM * FDIM + 128 * 64) {
    int j = i - HDIM * FDIM;
    int c = j / 64, k = j % 64;
    W1t[j] = f2bf(W1[(size_t)k * 128 + c]);
  } else if (i < HDIM * FDIM + 128 * 64 + 16 * 128) {
    int j = i - HDIM * FDIM - 128 * 64;
    int c = j / 128, k = j % 128;
    W2t[j] = f2bf(W2[(size_t)k * 16 + c]);
  }
}

// ---- proj = emb @ Wfc (bf16 MFMA, f32 A converted inline) + fused attn dots -
__global__ __launch_bounds__(256) void proj_gemm_kernel(
    const float* __restrict__ emb,              // [V][256] f32
    const unsigned short* __restrict__ Wt,      // [192][256] bf16
    const float* __restrict__ attn_l,           // [3][64] = [192]
    const float* __restrict__ attn_r,
    unsigned short* __restrict__ proj_bf,       // [V][192]
    float4* __restrict__ elv4, float4* __restrict__ erv4, int V)
{
  const int wave = threadIdx.x >> 6;
  const int lane = threadIdx.x & 63;
  const int row0 = blockIdx.x * 64 + wave * 16;
  const int cb = lane & 15;
  const int q  = lane >> 4;
  int arow = row0 + cb;
  if (arow >= V) arow = V - 1;                  // clamp loads; stores guarded
  const int kgrp = q * 8;

  f32x4 acc[12];
#pragma unroll
  for (int c = 0; c < 12; ++c) acc[c] = (f32x4){0.f, 0.f, 0.f, 0.f};

  const float* arow_p = &emb[(size_t)arow * HDIM + kgrp];
  const unsigned short* bcol_p = &Wt[(size_t)cb * HDIM + kgrp];

#pragma unroll
  for (int ks = 0; ks < 8; ++ks) {
    float4 f0 = *reinterpret_cast<const float4*>(arow_p + ks * 32);
    float4 f1 = *reinterpret_cast<const float4*>(arow_p + ks * 32 + 4);
    bf16x8 a;
    a[0] = (short)f2bf(f0.x); a[1] = (short)f2bf(f0.y);
    a[2] = (short)f2bf(f0.z); a[3] = (short)f2bf(f0.w);
    a[4] = (short)f2bf(f1.x); a[5] = (short)f2bf(f1.y);
    a[6] = (short)f2bf(f1.z); a[7] = (short)f2bf(f1.w);
#pragma unroll
    for (int c = 0; c < 12; ++c) {
      bf16x8 b = *reinterpret_cast<const bf16x8*>(bcol_p + (size_t)c * 16 * HDIM + ks * 32);
      acc[c] = __builtin_amdgcn_mfma_f32_16x16x32_bf16(a, b, acc[c], 0, 0, 0);
    }
  }

  const int rb = row0 + 4 * q;
#pragma unroll
  for (int i = 0; i < 4; ++i) {
    int r = rb + i;
    if (r < V) {
#pragma unroll
      for (int c = 0; c < 12; ++c)
        proj_bf[(size_t)r * FDIM + c * 16 + cb] = f2bf(acc[c][i]);
    }
  }

  // fused attention dots
  float al_v[12], ar_v[12];
#pragma unroll
  for (int c = 0; c < 12; ++c) {
    al_v[c] = attn_l[c * 16 + cb];
    ar_v[c] = attn_r[c * 16 + cb];
  }
  float elp[4][3], erp[4][3];
#pragma unroll
  for (int i = 0; i < 4; ++i)
#pragma unroll
    for (int h = 0; h < 3; ++h) {
      float sl = 0.f, sr = 0.f;
#pragma unroll
      for (int cc = 0; cc < 4; ++cc) {
        float v = acc[h * 4 + cc][i];
        sl += v * al_v[h * 4 + cc];
        sr += v * ar_v[h * 4 + cc];
      }
      elp[i][h] = sl; erp[i][h] = sr;
    }
#pragma unroll
  for (int s = 8; s > 0; s >>= 1) {
#pragma unroll
    for (int i = 0; i < 4; ++i)
#pragma unroll
      for (int h = 0; h < 3; ++h) {
        elp[i][h] += __shfl_xor(elp[i][h], s, 64);
        erp[i][h] += __shfl_xor(erp[i][h], s, 64);
      }
  }
  if (cb == 0) {
#pragma unroll
    for (int i = 0; i < 4; ++i) {
      int r = rb + i;
      if (r < V) {
        elv4[r] = make_float4(elp[i][0], elp[i][1], elp[i][2], 0.f);
        erv4[r] = make_float4(erp[i][0], erp[i][1], erp[i][2], 0.f);
      }
    }
  }
}

// ---------------- hist + rank: rank[e] = old count of dst -------------------
__global__ __launch_bounds__(256) void hist_kernel(
    const int* __restrict__ dst, int* __restrict__ cnt,
    unsigned short* __restrict__ rank16, int E)
{
  int e = blockIdx.x * 256 + threadIdx.x;
  if (e < E) rank16[e] = (unsigned short)atomicAdd(&cnt[dst[e]], 1);
}

__global__ __launch_bounds__(256) void scan_sum_kernel(
    const int* __restrict__ cnt, int* __restrict__ bsum, int n)
{
  __shared__ int red[256];
  int t = threadIdx.x;
  int base = blockIdx.x * 1024 + t * 4;
  int s = 0;
#pragma unroll
  for (int j = 0; j < 4; ++j) if (base + j < n) s += cnt[base + j];
  red[t] = s;
  __syncthreads();
  for (int o = 128; o > 0; o >>= 1) {
    if (t < o) red[t] += red[t + o];
    __syncthreads();
  }
  if (t == 0) bsum[blockIdx.x] = red[0];
}

__global__ void scan_bsum_kernel(int* bsum, int nb)
{
  if (threadIdx.x == 0 && blockIdx.x == 0) {
    int acc = 0;
    for (int i = 0; i < nb; ++i) { int v = bsum[i]; bsum[i] = acc; acc += v; }
  }
}

__global__ __launch_bounds__(256) void scan_write_kernel(
    const int* __restrict__ cnt, const int* __restrict__ bsum,
    int* __restrict__ offs, int n, int total)
{
  __shared__ int sd[256];
  int t = threadIdx.x;
  int base = blockIdx.x * 1024 + t * 4;
  int c[4];
  int ts = 0;
#pragma unroll
  for (int j = 0; j < 4; ++j) { c[j] = (base + j < n) ? cnt[base + j] : 0; ts += c[j]; }
  sd[t] = ts;
  __syncthreads();
  for (int o = 1; o < 256; o <<= 1) {
    int v = (t >= o) ? sd[t - o] : 0;
    __syncthreads();
    sd[t] += v;
    __syncthreads();
  }
  int run = sd[t] - ts + bsum[blockIdx.x];
#pragma unroll
  for (int j = 0; j < 4; ++j) {
    if (base + j < n) offs[base + j] = run;
    run += c[j];
  }
  if (blockIdx.x == 0 && t == 0) offs[n] = total;
}

// ---------------- scatter: recs16[offs[d]+rank[e]] = vocab(src) -------------
__global__ __launch_bounds__(256) void scatter_kernel(
    const int* __restrict__ src, const int* __restrict__ dst,
    const int* __restrict__ h0, const unsigned short* __restrict__ rank16,
    const int* __restrict__ offs, unsigned short* __restrict__ recs16, int E)
{
  int e = blockIdx.x * 256 + threadIdx.x;
  if (e >= E) return;
  int p = offs[dst[e]] + (int)rank16[e];
  recs16[p] = (unsigned short)h0[src[e]];
}

// ---------------- fused aggregation: per-wave 2-phase (w-exp + gather/FMA) --
// phase1: lane j computes w for edge c+j (1 exp set per EDGE); phase2: shuffle-
// broadcast (v,w) and do 8-wide batched proj gathers + FMA. No wrec/inv bufs.
__global__ __launch_bounds__(256) void aggregate_kernel(
    const unsigned short* __restrict__ recs16, const int* __restrict__ offs,
    const int* __restrict__ h0,
    const unsigned short* __restrict__ proj_bf,
    const float4* __restrict__ elv4, const float4* __restrict__ erv4,
    const float* __restrict__ bias_gat,
    unsigned short* __restrict__ h2bf, int N)
{
  int lane = threadIdx.x & 63;
  int n = blockIdx.x * 4 + (threadIdx.x >> 6);
  if (n >= N) return;
  const float4 ero = erv4[h0[n]];
  int lo = offs[n], hi = offs[n + 1];
  float a0 = 0.f, a1 = 0.f, a2 = 0.f, d0 = 0.f, d1 = 0.f, d2 = 0.f;

  for (int c = lo; c < hi; c += 64) {
    int m = hi - c; if (m > 64) m = 64;
    // ---- phase 1: one edge per lane
    int v = 0; float w0 = 0.f, w1 = 0.f, w2 = 0.f;
    if (lane < m) {
      v = recs16[c + lane];
      float4 ev = elv4[v];
      float e0 = ev.x + ero.x, e1 = ev.y + ero.y, e2 = ev.z + ero.z;
      e0 = e0 > 0.f ? e0 : 0.2f * e0;   // leaky_relu 0.2
      e1 = e1 > 0.f ? e1 : 0.2f * e1;
      e2 = e2 > 0.f ? e2 : 0.2f * e2;
      w0 = __expf(e0); w1 = __expf(e1); w2 = __expf(e2);
      d0 += w0; d1 += w1; d2 += w2;
    }
    // ---- phase 2: broadcast via shuffle, 8-wide batched gathers
    int j = 0;
    for (; j + 8 <= m; j += 8) {
      int vv[8]; float u0[8], u1[8], u2[8];
#pragma unroll
      for (int t = 0; t < 8; ++t) {
        vv[t] = __shfl(v,  j + t, 64);
        u0[t] = __shfl(w0, j + t, 64);
        u1[t] = __shfl(w1, j + t, 64);
        u2[t] = __shfl(w2, j + t, 64);
      }
      const unsigned short* ps[8];
#pragma unroll
      for (int t = 0; t < 8; ++t) ps[t] = &proj_bf[(size_t)vv[t] * FDIM];
      float g0[8], g1[8], g2[8];
#pragma unroll
      for (int t = 0; t < 8; ++t) {     // 24 independent gathers in flight
        g0[t] = bf2f(ps[t][lane]);
        g1[t] = bf2f(ps[t][64 + lane]);
        g2[t] = bf2f(ps[t][128 + lane]);
      }
#pragma unroll
      for (int t = 0; t < 8; ++t) {
        a0 += u0[t] * g0[t]; a1 += u1[t] * g1[t]; a2 += u2[t] * g2[t];
      }
    }
    for (; j < m; ++j) {
      int vv = __shfl(v, j, 64);
      float u0 = __shfl(w0, j, 64), u1 = __shfl(w1, j, 64), u2 = __shfl(w2, j, 64);
      const unsigned short* ps = &proj_bf[(size_t)vv * FDIM];
      a0 += u0 * bf2f(ps[lane]);
      a1 += u1 * bf2f(ps[64 + lane]);
      a2 += u2 * bf2f(ps[128 + lane]);
    }
  }

  // reduce denominators across lanes (inactive lanes contributed 0)
#pragma unroll
  for (int s = 32; s > 0; s >>= 1) {
    d0 += __shfl_xor(d0, s, 64);
    d1 += __shfl_xor(d1, s, 64);
    d2 += __shfl_xor(d2, s, 64);
  }
  float i0 = d0 > 0.f ? 1.f / d0 : 0.f;   // guard 0-in-degree
  float i1 = d1 > 0.f ? 1.f / d1 : 0.f;
  float i2 = d2 > 0.f ? 1.f / d2 : 0.f;
  float r0 = a0 * i0 + bias_gat[lane];
  float r1 = a1 * i1 + bias_gat[64 + lane];
  float r2 = a2 * i2 + bias_gat[128 + lane];
  float h2 = (fmaxf(r0, 0.f) + fmaxf(r1, 0.f) + fmaxf(r2, 0.f)) * (1.f / 3.f);
  h2bf[(size_t)n * 64 + lane] = f2bf(h2);
}

// ---------------- MLP via MFMA: relu(h2@W1+b1)@W2+b2 + graph atomics --------
__global__ __launch_bounds__(256) void post_mfma_kernel(
    const unsigned short* __restrict__ h2bf,   // [N][64]
    const unsigned short* __restrict__ W1t,    // [128][64]
    const float* __restrict__ b1,
    const unsigned short* __restrict__ W2t,    // [16][128]
    const float* __restrict__ b2, const int* __restrict__ gid,
    float* __restrict__ sums_priv, float* __restrict__ counts_priv, int N)
{
  __shared__ unsigned short z_lds[64 * 128];
  const int wave = threadIdx.x >> 6;
  const int lane = threadIdx.x & 63;
  const int r = lane & 15;
  const int q = lane >> 4;
  const int kg = q * 8;
  const int rw0 = blockIdx.x * 64 + wave * 16;

  int arow = rw0 + r;
  if (arow >= N) arow = N - 1;       // clamp loads; stores guarded

  f32x4 acc1[8];
#pragma unroll
  for (int c = 0; c < 8; ++c) acc1[c] = (f32x4){0.f, 0.f, 0.f, 0.f};

#pragma unroll
  for (int ks = 0; ks < 2; ++ks) {
    bf16x8 a = *reinterpret_cast<const bf16x8*>(&h2bf[(size_t)arow * 64 + kg + ks * 32]);
#pragma unroll
    for (int c = 0; c < 8; ++c) {
      bf16x8 b = *reinterpret_cast<const bf16x8*>(&W1t[(size_t)(c * 16 + r) * 64 + kg + ks * 32]);
      acc1[c] = __builtin_amdgcn_mfma_f32_16x16x32_bf16(a, b, acc1[c], 0, 0, 0);
    }
  }
#pragma unroll
  for (int c = 0; c < 8; ++c) {
    float bb = b1[c * 16 + r];
#pragma unroll
    for (int i = 0; i < 4; ++i) {
      float z = acc1[c][i] + bb;
      z = z > 0.f ? z : 0.f;
      z_lds[(wave * 16 + 4 * q + i) * 128 + c * 16 + r] = f2bf(z);
    }
  }
  __syncthreads();

  f32x4 acc2 = (f32x4){0.f, 0.f, 0.f, 0.f};
#pragma unroll
  for (int ks = 0; ks < 4; ++ks) {
    bf16x8 a = *reinterpret_cast<const bf16x8*>(&z_lds[(wave * 16 + r) * 128 + kg + ks * 32]);
    bf16x8 b = *reinterpret_cast<const bf16x8*>(&W2t[(size_t)r * 128 + kg + ks * 32]);
    acc2 = __builtin_amdgcn_mfma_f32_16x16x32_bf16(a, b, acc2, 0, 0, 0);
  }
  const int part = blockIdx.x & (NPART - 1);
  float bb2 = b2[r];
#pragma unroll
  for (int i = 0; i < 4; ++i) {
    int row = rw0 + 4 * q + i;
    if (row < N) {
      int g = gid[row];
      atomicAdd(&sums_priv[(part * NGRAPH + g) * 16 + r], acc2[i] + bb2);
      if (r == 0) atomicAdd(&counts_priv[part * NGRAPH + g], 1.f);
    }
  }
}

// ---------------- reduce privatized graph sums -> output --------------------
__global__ void finalize_kernel(const float* __restrict__ sums_priv,
                                const float* __restrict__ counts_priv,
                                float* __restrict__ out)
{
  int j = threadIdx.x;            // 0..1023  (g*16 + col)
  int g = j >> 4;
  float s = 0.f, c = 0.f;
  for (int p = 0; p < NPART; ++p) {
    s += sums_priv[p * NGRAPH * 16 + j];
    c += counts_priv[p * NGRAPH + g];
  }
  out[j] = s / fmaxf(c, 1.f);
}

extern "C" void kernel_launch(void* const* d_in, const int* in_sizes, int n_in,
                              void* d_out, int out_size, void* d_ws, size_t ws_size,
                              hipStream_t stream)
{
  const int*   h0  = (const int*)  d_in[0];
  const int*   src = (const int*)  d_in[1];
  const int*   dst = (const int*)  d_in[2];
  const int*   gid = (const int*)  d_in[3];
  const float* emb = (const float*)d_in[4];
  const float* Wfc = (const float*)d_in[5];
  const float* al  = (const float*)d_in[6];
  const float* ar  = (const float*)d_in[7];
  const float* bg  = (const float*)d_in[8];
  const float* W1  = (const float*)d_in[9];
  const float* b1  = (const float*)d_in[10];
  const float* W2  = (const float*)d_in[11];
  const float* b2  = (const float*)d_in[12];
  float* out = (float*)d_out;

  char* ws = (char*)d_ws;
  size_t off = 0;
  auto alloc = [&](size_t bytes) -> void* {
    off = (off + 255) & ~(size_t)255;
    void* p = ws + off;
    off += bytes;
    return p;
  };
  unsigned short* Wt      = (unsigned short*)alloc((size_t)FDIM * HDIM * 2);
  unsigned short* W1t     = (unsigned short*)alloc((size_t)128 * 64 * 2);
  unsigned short* W2t     = (unsigned short*)alloc((size_t)16 * 128 * 2);
  unsigned short* proj_bf = (unsigned short*)alloc((size_t)VOCAB * FDIM * 2);
  unsigned short* h2bf    = (unsigned short*)alloc((size_t)NNODES * 64 * 2);
  unsigned short* recs16  = (unsigned short*)alloc((size_t)NEDGES * 2);
  unsigned short* rank16  = (unsigned short*)alloc((size_t)NEDGES * 2);
  float4* elv4   = (float4*)alloc((size_t)VOCAB * 16);
  float4* erv4   = (float4*)alloc((size_t)VOCAB * 16);
  int*    cnt    = (int*)   alloc((size_t)NNODES * 4);
  int*    offs   = (int*)   alloc((size_t)(NNODES + 1) * 4);
  int*    bsum   = (int*)   alloc((size_t)128 * 4);
  float*  sums   = (float*) alloc((size_t)NPART * NGRAPH * 16 * 4);
  float*  cnts   = (float*) alloc((size_t)NPART * NGRAPH * 4);

  hipMemsetAsync(cnt,  0, (size_t)NNODES * 4, stream);
  hipMemsetAsync(sums, 0, (size_t)NPART * NGRAPH * 16 * 4, stream);
  hipMemsetAsync(cnts, 0, (size_t)NPART * NGRAPH * 4, stream);

  const int NB = (NNODES + 1023) / 1024;   // 98

  conv_weights_kernel<<<(HDIM * FDIM + 128 * 64 + 16 * 128 + 255) / 256, 256, 0, stream>>>(
      Wfc, W1, W2, Wt, W1t, W2t);
  proj_gemm_kernel<<<(VOCAB + 63) / 64, 256, 0, stream>>>(emb, Wt, al, ar,
                                                          proj_bf, elv4, erv4, VOCAB);
  hist_kernel<<<(NEDGES + 255) / 256, 256, 0, stream>>>(dst, cnt, rank16, NEDGES);
  scan_sum_kernel<<<NB, 256, 0, stream>>>(cnt, bsum, NNODES);
  scan_bsum_kernel<<<1, 64, 0, stream>>>(bsum, NB);
  scan_write_kernel<<<NB, 256, 0, stream>>>(cnt, bsum, offs, NNODES, NEDGES);
  scatter_kernel<<<(NEDGES + 255) / 256, 256, 0, stream>>>(src, dst, h0, rank16, offs,
                                                           recs16, NEDGES);
  aggregate_kernel<<<(NNODES + 3) / 4, 256, 0, stream>>>(recs16, offs, h0, proj_bf,
                                                         elv4, erv4, bg, h2bf, NNODES);
  post_mfma_kernel<<<(NNODES + 63) / 64, 256, 0, stream>>>(h2bf, W1t, b1, W2t, b2, gid,
                                                           sums, cnts, NNODES);
  finalize_kernel<<<1, 1024, 0, stream>>>(sums, cnts, out);
}